// Round 10
// baseline (358.201 us; speedup 1.0000x reference)
//
#include <hip/hip_runtime.h>

typedef __attribute__((ext_vector_type(8))) short short8;
typedef __attribute__((ext_vector_type(4))) float f32x4;

__device__ __forceinline__ float sigmoidf_(float x) { return 1.f / (1.f + __expf(-x)); }
__device__ __forceinline__ unsigned bf16rne(float x) {
    unsigned b = __float_as_uint(x);
    return (b + 0x7FFFu + ((b >> 16) & 1u)) >> 16;
}

// ws layout (float words):
//   OFFM:  lvl0 @0 (2359296), lvl1 @2359296 (589824), lvl2 @2949120 (147456)
//   MOD:   lvl0 @3096576 (1179648), lvl1 @4276224 (294912), lvl2 @4571136 (73728)
//   MEAN:  lvl0 @4644864 (65536), lvl1 @4710400 (16384), lvl2 @4726784 (4096)
//   WREP:  @4730880, 3*62784; per lvl: [18432 u32 WB (MFMA B-frags)]
//                                      [pad to 36864][5184 off][20736 mod]
//   S:     @4919232 (uints), lvl0 +0, lvl1 +9437184, lvl2 +11796480
// XT lives in d_out's feat region (consumed in K2, overwritten in K3):
//   lvl0 @out+655360, lvl1 @out+131072, lvl2 @out+0

struct P {
    const float *sou0, *sou1, *sou2;
    const float *ref0, *ref1, *ref2;
    const float *ob0, *ob1, *ob2;
    const float *mb0, *mb1, *mb2;
    float* out;
    float* ws;
};

// ---------------- K0: fused weight repack (all levels) --------------------------------
__global__ __launch_bounds__(256) void repack_all(
    const float* __restrict__ ow0, const float* __restrict__ mw0, const float* __restrict__ rw0,
    const float* __restrict__ ow1, const float* __restrict__ mw1, const float* __restrict__ rw1,
    const float* __restrict__ ow2, const float* __restrict__ mw2, const float* __restrict__ rw2,
    float* __restrict__ dst) {
    const int lvl = blockIdx.y;
    const float* ow = lvl == 0 ? ow0 : (lvl == 1 ? ow1 : ow2);
    const float* mw = lvl == 0 ? mw0 : (lvl == 1 ? mw1 : mw2);
    const float* rw = lvl == 0 ? rw0 : (lvl == 1 ? rw1 : rw2);
    float* d = dst + lvl * 62784;
    int i = blockIdx.x * 256 + threadIdx.x;
    if (i < 18432) {  // WB: ((wvu*18+ks)*64+lane)*4+jw  (u32 = bf16 c0 | bf16 c0+1 <<16)
        int jw = i & 3;
        int lane = (i >> 2) & 63;
        int t3 = i >> 8;
        int ks = t3 % 18, wvu = t3 / 18;
        int o = wvu * 16 + (lane & 15);
        int c0 = ks * 32 + (lane >> 4) * 8 + 2 * jw;
        int g0 = c0 / 144, r0 = c0 % 144;
        int c1 = c0 + 1;
        int g1 = c1 / 144, r1 = c1 % 144;
        float w0 = rw[o * 576 + (g0 * 16 + (r0 & 15)) * 9 + (r0 >> 4)];
        float w1 = rw[o * 576 + (g1 * 16 + (r1 & 15)) * 9 + (r1 >> 4)];
        ((unsigned*)d)[i] = bf16rne(w0) | (bf16rne(w1) << 16);
    }
    if (i < 5184) {   // off -> [ic][k][18]
        int oc = i % 18, k = (i / 18) % 9, ic = i / 162;
        d[36864 + i] = ow[oc * 288 + ic * 9 + k];
    }
    if (i < 20736) {  // mod -> [ic][k][36]
        int oc = i % 36, k = (i / 36) % 9, ic = i / 324;
        d[42048 + i] = mw[oc * 576 + ic * 9 + k];
    }
}

// ---------------- K1: offset_conv(336) + mod_conv(336) + transpose(672) ---------------
// 2 px/thread (R9's 4px gave only 336 conv blocks = 1.3/CU -> 1 wave/SIMD tail,
// VALUBusy 28%). 2px doubles conv blocks to 1344 (5.25/CU, ~21 waves/CU) while keeping
// 36 FMA/load. No launch_bounds (R5/R6: bound w caps VGPR ~256/w -> spills).
__global__ __launch_bounds__(256) void k1_prep(P p) {
    __shared__ float tile[256][17];
    const int t = blockIdx.x;
    int task, i;
    if (t < 336) { task = 0; i = t; }
    else if (t < 672) { task = 1; i = t - 336; }
    else { task = 2; i = t - 672; }
    float* ws = p.ws;

    if (task == 0) {  // ---- offset conv: 32ch(concat) -> 18, sigmoid map, 2 px/thread
        int lvl, j;
        if (i < 256) { lvl = 0; j = i; }
        else if (i < 320) { lvl = 1; j = i - 256; }
        else { lvl = 2; j = i - 320; }
        const int logW = 7 - lvl;
        const int W = 1 << logW, H = W, HW = H * W;
        const int nper = 32 >> (2 * lvl);
        const int qb = j % nper, g = (j / nper) & 3, b = j / (nper * 4);
        const int q = qb * 512 + (int)threadIdx.x * 2;
        const int h = q >> logW, x0 = q & (W - 1);
        const float* sou = lvl == 0 ? p.sou0 : (lvl == 1 ? p.sou1 : p.sou2);
        const float* ref = lvl == 0 ? p.ref0 : (lvl == 1 ? p.ref1 : p.ref2);
        const float* wt = ws + 4730880 + lvl * 62784 + 36864;
        const float* bias = lvl == 0 ? p.ob0 : (lvl == 1 ? p.ob1 : p.ob2);
        float* OFFM = ws + (lvl == 0 ? 0 : (lvl == 1 ? 2359296 : 2949120));
        const float rng = 0.25f * (float)H;
        float acc[2][18];
#pragma unroll
        for (int px = 0; px < 2; ++px)
#pragma unroll
            for (int u = 0; u < 18; ++u) acc[px][u] = 0.f;
        const float* base_s = sou + (size_t)(b * 64 + g * 16) * HW;
        const float* base_r = ref + (size_t)(b * 64 + g * 16) * HW;
        for (int ic = 0; ic < 32; ++ic) {
            const float* plane = (ic < 16) ? base_s + (size_t)ic * HW
                                           : base_r + (size_t)(ic - 16) * HW;
            const float* wp = wt + ic * 162;
#pragma unroll
            for (int ky = 0; ky < 3; ++ky) {
                int yy = h + ky - 1;
                bool yok = (yy >= 0) && (yy < H);
                const float* row = plane + (size_t)min(max(yy, 0), H - 1) * W;
                float w[4];
                float2 f2 = yok ? *(const float2*)(row + x0) : make_float2(0.f, 0.f);
                w[0] = (yok && x0 > 0) ? row[x0 - 1] : 0.f;
                w[1] = f2.x; w[2] = f2.y;
                w[3] = (yok && x0 + 2 < W) ? row[x0 + 2] : 0.f;
#pragma unroll
                for (int kx = 0; kx < 3; ++kx) {
                    const float* wk = wp + (ky * 3 + kx) * 18;
#pragma unroll
                    for (int oc = 0; oc < 18; ++oc) {
                        float wv = wk[oc];
#pragma unroll
                        for (int px = 0; px < 2; ++px)
                            acc[px][oc] = fmaf(w[px + kx], wv, acc[px][oc]);
                    }
                }
            }
        }
#pragma unroll
        for (int oc = 0; oc < 18; ++oc) {
            float r0 = acc[0][oc] + bias[oc], r1 = acc[1][oc] + bias[oc];
            r0 = rng * (2.f * sigmoidf_(r0) - 1.f);
            r1 = rng * (2.f * sigmoidf_(r1) - 1.f);
            *(float2*)&OFFM[(size_t)(b * 72 + g * 18 + oc) * HW + q] = make_float2(r0, r1);
        }
    } else if (task == 1) {  // ---- modulator conv: 64 -> 36, wave oc-split, 2 px/lane
        int lvl, j;
        if (i < 256) { lvl = 0; j = i; }
        else if (i < 320) { lvl = 1; j = i - 256; }
        else { lvl = 2; j = i - 320; }
        const int logW = 7 - lvl;
        const int W = 1 << logW, H = W, HW = H * W;
        const int nper = 128 >> (2 * lvl);
        const int qb = j % nper, b = j / nper;
        const int o0 = __builtin_amdgcn_readfirstlane((int)threadIdx.x >> 6) * 9;
        const int lane = threadIdx.x & 63;
        const int q = qb * 128 + lane * 2;
        const int h = q >> logW, x0 = q & (W - 1);
        const float* sou = lvl == 0 ? p.sou0 : (lvl == 1 ? p.sou1 : p.sou2);
        const float* wt = ws + 4730880 + lvl * 62784 + 42048;
        const float* bias = lvl == 0 ? p.mb0 : (lvl == 1 ? p.mb1 : p.mb2);
        float* MOD = ws + (lvl == 0 ? 3096576 : (lvl == 1 ? 4276224 : 4571136));
        float acc[2][9];
#pragma unroll
        for (int px = 0; px < 2; ++px)
#pragma unroll
            for (int u = 0; u < 9; ++u) acc[px][u] = 0.f;
        const float* base = sou + (size_t)b * 64 * HW;
        for (int ic = 0; ic < 64; ++ic) {
            const float* plane = base + (size_t)ic * HW;
            const float* wp = wt + ic * 324 + o0;
#pragma unroll
            for (int ky = 0; ky < 3; ++ky) {
                int yy = h + ky - 1;
                bool yok = (yy >= 0) && (yy < H);
                const float* row = plane + (size_t)min(max(yy, 0), H - 1) * W;
                float w[4];
                float2 f2 = yok ? *(const float2*)(row + x0) : make_float2(0.f, 0.f);
                w[0] = (yok && x0 > 0) ? row[x0 - 1] : 0.f;
                w[1] = f2.x; w[2] = f2.y;
                w[3] = (yok && x0 + 2 < W) ? row[x0 + 2] : 0.f;
#pragma unroll
                for (int kx = 0; kx < 3; ++kx) {
                    const float* wk = wp + (ky * 3 + kx) * 36;
#pragma unroll
                    for (int oc = 0; oc < 9; ++oc) {
                        float wv = wk[oc];
#pragma unroll
                        for (int px = 0; px < 2; ++px)
                            acc[px][oc] = fmaf(w[px + kx], wv, acc[px][oc]);
                    }
                }
            }
        }
#pragma unroll
        for (int oc = 0; oc < 9; ++oc) {
            float r0 = 2.f * sigmoidf_(acc[0][oc] + bias[o0 + oc]);
            float r1 = 2.f * sigmoidf_(acc[1][oc] + bias[o0 + oc]);
            *(float2*)&MOD[(size_t)(b * 36 + o0 + oc) * HW + q] = make_float2(r0, r1);
        }
    } else {  // ---- transpose (b,64,H,W) -> XT (b,g,HW,16)
        int lvl, j;
        if (i < 512) { lvl = 0; j = i; }
        else if (i < 640) { lvl = 1; j = i - 512; }
        else { lvl = 2; j = i - 640; }
        const int HW = 16384 >> (2 * lvl);
        const int nper = 64 >> (2 * lvl);
        const int qb = j % nper, g = (j / nper) & 3, b = j / (nper * 4);
        const float* sou = lvl == 0 ? p.sou0 : (lvl == 1 ? p.sou1 : p.sou2);
        float* XT = p.out + (lvl == 0 ? 655360 : (lvl == 1 ? 131072 : 0));
        const int tt = threadIdx.x;
        const int q0 = qb * 256;
        const float* src = sou + (size_t)(b * 64 + g * 16) * HW + q0;
#pragma unroll
        for (int c = 0; c < 16; ++c) tile[tt][c] = src[(size_t)c * HW + tt];
        __syncthreads();
        float4* dst = (float4*)(XT + ((size_t)(b * 4 + g) * HW + q0) * 16);
#pragma unroll
        for (int u = 0; u < 4; ++u) {
            int f4 = u * 256 + tt;
            int q = f4 >> 2, c4 = (f4 & 3) * 4;
            dst[f4] = make_float4(tile[q][c4], tile[q][c4 + 1], tile[q][c4 + 2], tile[q][c4 + 3]);
        }
    }
}

// ---------------- K2: gather(6048) + mean(168) ----------------------------------------
__global__ __launch_bounds__(256) void k2_gather(P p) {
    const int t = blockIdx.x;
    float* ws = p.ws;
    if (t < 6048) {
        int lvl, j;
        if (t < 4608) { lvl = 0; j = t; }
        else if (t < 5760) { lvl = 1; j = t - 4608; }
        else { lvl = 2; j = t - 5760; }
        const int logW = 7 - lvl;
        const int W = 1 << logW, H = W, HW = H * W;
        const int nper = 64 >> (2 * lvl);
        const int qb = j % nper, gk = (j / nper) % 36, b = j / (nper * 36);
        const int g = gk / 9, k = gk - g * 9;
        const float* OFFM = ws + (lvl == 0 ? 0 : (lvl == 1 ? 2359296 : 2949120));
        const float* MOD = ws + (lvl == 0 ? 3096576 : (lvl == 1 ? 4276224 : 4571136));
        const float* XT = p.out + (lvl == 0 ? 655360 : (lvl == 1 ? 131072 : 0));
        unsigned* S = (unsigned*)(ws + 4919232) + (lvl == 0 ? 0 : (lvl == 1 ? 9437184 : 11796480));
        const int q = qb * 256 + threadIdx.x;
        const int h = q >> logW, xp = q & (W - 1);
        const int ky = k / 3, kx = k - ky * 3;
        float dy = OFFM[(size_t)(b * 72 + g * 18 + 2 * k) * HW + q];
        float dx = OFFM[(size_t)(b * 72 + g * 18 + 2 * k + 1) * HW + q];
        float m = MOD[(size_t)(b * 36 + g * 9 + k) * HW + q];
        float py = (float)(h - 1 + ky) + dy;
        float px = (float)(xp - 1 + kx) + dx;
        float y0f = floorf(py), x0f = floorf(px);
        float wy = py - y0f, wx = px - x0f;
        int y0 = (int)y0f, x0 = (int)x0f;
        const float* xg = XT + (size_t)(b * 4 + g) * HW * 16;
        float s[16];
#pragma unroll
        for (int c = 0; c < 16; ++c) s[c] = 0.f;
#pragma unroll
        for (int cor = 0; cor < 4; ++cor) {
            int yy = y0 + (cor >> 1), xx = x0 + (cor & 1);
            float cw = ((cor >> 1) ? wy : 1.f - wy) * ((cor & 1) ? wx : 1.f - wx);
            cw = (yy >= 0 && yy < H && xx >= 0 && xx < W) ? cw * m : 0.f;
            int yc = min(max(yy, 0), H - 1), xc = min(max(xx, 0), W - 1);
            const float4* pp = (const float4*)(xg + (size_t)((yc << logW) + xc) * 16);
            float4 v0 = pp[0], v1 = pp[1], v2 = pp[2], v3 = pp[3];
            s[0] = fmaf(cw, v0.x, s[0]);   s[1] = fmaf(cw, v0.y, s[1]);
            s[2] = fmaf(cw, v0.z, s[2]);   s[3] = fmaf(cw, v0.w, s[3]);
            s[4] = fmaf(cw, v1.x, s[4]);   s[5] = fmaf(cw, v1.y, s[5]);
            s[6] = fmaf(cw, v1.z, s[6]);   s[7] = fmaf(cw, v1.w, s[7]);
            s[8] = fmaf(cw, v2.x, s[8]);   s[9] = fmaf(cw, v2.y, s[9]);
            s[10] = fmaf(cw, v2.z, s[10]); s[11] = fmaf(cw, v2.w, s[11]);
            s[12] = fmaf(cw, v3.x, s[12]); s[13] = fmaf(cw, v3.y, s[13]);
            s[14] = fmaf(cw, v3.z, s[14]); s[15] = fmaf(cw, v3.w, s[15]);
        }
        unsigned* Sp = S + (size_t)(b * 288 + gk * 8) * HW + q;
#pragma unroll
        for (int pr = 0; pr < 8; ++pr) {
            unsigned u = bf16rne(s[2 * pr]) | (bf16rne(s[2 * pr + 1]) << 16);
            Sp[(size_t)pr * HW] = u;
        }
    } else {
        int i = t - 6048;
        int lvl, j;
        if (i < 128) { lvl = 0; j = i; }
        else if (i < 160) { lvl = 1; j = i - 128; }
        else { lvl = 2; j = i - 160; }
        const int HW = 16384 >> (2 * lvl);
        const int nper = 64 >> (2 * lvl);
        const int qb = j % nper, b = j / nper;
        const float* OFFM = ws + (lvl == 0 ? 0 : (lvl == 1 ? 2359296 : 2949120));
        float* MEAN = ws + (lvl == 0 ? 4644864 : (lvl == 1 ? 4710400 : 4726784));
        const int q = qb * 256 + threadIdx.x;
        const float* pp = OFFM + (size_t)b * 72 * HW + q;
        float sy = 0.f, sx = 0.f;
#pragma unroll
        for (int u = 0; u < 36; ++u) {
            sy += pp[(size_t)(2 * u) * HW];
            sx += pp[(size_t)(2 * u + 1) * HW];
        }
        MEAN[(size_t)(b * 2) * HW + q] = sy * (1.f / 36.f);
        MEAN[(size_t)(b * 2 + 1) * HW + q] = sx * (1.f / 36.f);
    }
}

// ---------------- K3: MFMA dgemm(672, 2x144-row LDS chunks) + upsample(3072) ----------
__global__ __launch_bounds__(256) void k3_out(P p) {
    __shared__ unsigned lds[144 * 64];  // 36 KB -> 4 blocks/CU
    const int t = blockIdx.x;
    float* ws = p.ws;
    if (t < 672) {
        int lvl, j;
        if (t < 512) { lvl = 0; j = t; }
        else if (t < 640) { lvl = 1; j = t - 512; }
        else { lvl = 2; j = t - 640; }
        const int HW = 16384 >> (2 * lvl);
        const int nper = 256 >> (2 * lvl);
        const int qb = j % nper, b = j / nper;
        const unsigned* S = (const unsigned*)(ws + 4919232) +
                            (lvl == 0 ? 0 : (lvl == 1 ? 9437184 : 11796480));
        const unsigned* WB = (const unsigned*)(ws + 4730880 + lvl * 62784);
        float* outp = p.out + (lvl == 0 ? 655360 : (lvl == 1 ? 131072 : 0));
        const int q0 = qb * 64;
        const int tid = threadIdx.x;
        const int wvu = __builtin_amdgcn_readfirstlane(tid >> 6);
        const int lane = tid & 63;
        const int quad = lane >> 4, lo16 = lane & 15;
        union U { uint4 u; int4 i; short8 s; f32x4 f; };
        f32x4 acc[4];
#pragma unroll
        for (int mt = 0; mt < 4; ++mt) acc[mt] = (f32x4){0.f, 0.f, 0.f, 0.f};
        for (int chk = 0; chk < 2; ++chk) {
            __syncthreads();
            const unsigned* Sb = S + (size_t)(b * 288 + chk * 144) * HW + q0;
            for (int i = tid; i < 144 * 16; i += 256) {
                int r = i >> 4, ch = (i & 15) << 2;
                *(uint4*)&lds[r * 64 + ch] = *(const uint4*)(Sb + (size_t)r * HW + ch);
            }
            __syncthreads();
            uint4 bfr[9];
#pragma unroll
            for (int k9 = 0; k9 < 9; ++k9)
                bfr[k9] = *(const uint4*)(WB + (((wvu * 18 + chk * 9 + k9) * 64 + lane) << 2));
#pragma unroll
            for (int k9 = 0; k9 < 9; ++k9) {
                const int rb = k9 * 16 + quad * 4;
                U bu; bu.u = bfr[k9];
#pragma unroll
                for (int mt = 0; mt < 4; ++mt) {
                    const int px = mt * 16 + lo16;
                    U au;
                    au.i.x = (int)lds[(rb + 0) * 64 + px];
                    au.i.y = (int)lds[(rb + 1) * 64 + px];
                    au.i.z = (int)lds[(rb + 2) * 64 + px];
                    au.i.w = (int)lds[(rb + 3) * 64 + px];
                    acc[mt] = __builtin_amdgcn_mfma_f32_16x16x32_bf16(au.s, bu.s, acc[mt], 0, 0, 0);
                }
            }
        }
        float* op = outp + (size_t)(b * 64 + wvu * 16 + lo16) * HW + q0;
#pragma unroll
        for (int mt = 0; mt < 4; ++mt)
#pragma unroll
            for (int rg = 0; rg < 4; ++rg)
                op[mt * 16 + quad * 4 + rg] = acc[mt][rg];
    } else {
        // upsample: 4 px/thread over flat [lvl][b][c][512][512]
        int i = t - 672;  // 0..3071
        int flat = (i * 256 + (int)threadIdx.x) * 4;
        int lvl = flat >> 20;
        int r = flat & 1048575;
        int b = r >> 19, c = (r >> 18) & 1;
        int pix = r & 262143;
        int yo = pix >> 9, xo = pix & 511;
        const int H = 128 >> lvl, W = H;
        const float* MEAN = ws + (lvl == 0 ? 4644864 : (lvl == 1 ? 4710400 : 4726784));
        const float* m = MEAN + (size_t)(b * 2 + c) * H * W;
        float* o = p.out + (lvl == 0 ? 4849664 : (lvl == 1 ? 3801088 : 2752512)) +
                   ((size_t)(b * 2 + c) * 512 + yo) * 512 + xo;
        const float fs = (float)(4 << lvl);
        const float sc = (float)(H - 1) * (1.f / 511.f);
        float sy = yo * sc;
        int y0 = min((int)sy, H - 2);
        float wy = sy - (float)y0;
        float rr[4];
#pragma unroll
        for (int u = 0; u < 4; ++u) {
            float sx = (float)(xo + u) * sc;
            int x0 = min((int)sx, W - 2);
            float wx = sx - (float)x0;
            float v00 = m[y0 * W + x0], v01 = m[y0 * W + x0 + 1];
            float v10 = m[(y0 + 1) * W + x0], v11 = m[(y0 + 1) * W + x0 + 1];
            float r0 = v00 * (1.f - wy) + v10 * wy;
            float r1 = v01 * (1.f - wy) + v11 * wy;
            rr[u] = (r0 * (1.f - wx) + r1 * wx) * fs;
        }
        *(float4*)o = make_float4(rr[0], rr[1], rr[2], rr[3]);
    }
}

extern "C" void kernel_launch(void* const* d_in, const int* in_sizes, int n_in,
                              void* d_out, int out_size, void* d_ws, size_t ws_size,
                              hipStream_t stream) {
    const float* fin[21];
    for (int i = 0; i < 21; ++i) fin[i] = (const float*)d_in[i];
    P p;
    if (in_sizes[1] == in_sizes[0]) {  // dict order sou1,ref1,sou2,ref2,sou3,ref3
        p.sou0 = fin[0]; p.ref0 = fin[1];
        p.sou1 = fin[2]; p.ref1 = fin[3];
        p.sou2 = fin[4]; p.ref2 = fin[5];
    } else {  // arg order
        p.sou0 = fin[0]; p.sou1 = fin[1]; p.sou2 = fin[2];
        p.ref0 = fin[3]; p.ref1 = fin[4]; p.ref2 = fin[5];
    }
    p.ob0 = fin[7]; p.mb0 = fin[9];
    p.ob1 = fin[12]; p.mb1 = fin[14];
    p.ob2 = fin[17]; p.mb2 = fin[19];
    p.out = (float*)d_out;
    p.ws = (float*)d_ws;

    repack_all<<<dim3(144, 3), 256, 0, stream>>>(
        fin[6], fin[8], fin[10], fin[11], fin[13], fin[15], fin[16], fin[18], fin[20],
        p.ws + 4730880);
    k1_prep<<<dim3(1344), 256, 0, stream>>>(p);
    k2_gather<<<dim3(6216), 256, 0, stream>>>(p);
    k3_out<<<dim3(3744), 256, 0, stream>>>(p);
}

// Round 11
// 296.835 us; speedup vs baseline: 1.2067x; 1.2067x over previous
//
#include <hip/hip_runtime.h>

typedef __attribute__((ext_vector_type(8))) short short8;
typedef __attribute__((ext_vector_type(4))) float f32x4;

__device__ __forceinline__ float sigmoidf_(float x) { return 1.f / (1.f + __expf(-x)); }
__device__ __forceinline__ unsigned bf16rne(float x) {
    unsigned b = __float_as_uint(x);
    return (b + 0x7FFFu + ((b >> 16) & 1u)) >> 16;
}
__device__ __forceinline__ float bf2f(unsigned short u) {
    return __uint_as_float(((unsigned)u) << 16);
}

// ws layout (float words):
//   OFFP (bf16 partials, 2 halves): words 0..3096576
//     ushort elem idx = half*3096576 + lvlbase{0,2359296,2949120} + (b*72+ch)*HW + q
//   MODP (bf16 partials, 2 halves): words 3096576..4644864
//     ushort elem idx = half*1548288 + lvlbase{0,1179648,1474560} + (b*36+ch)*HW + q
//   MEAN:  lvl0 @4644864 (65536), lvl1 @4710400 (16384), lvl2 @4726784 (4096)
//   WREP:  @4730880, 3*62784; per lvl: [18432 u32 WB (MFMA B-frags)]
//                                      [pad to 36864][5184 off][20736 mod]
//   S:     @4919232 (uints), lvl0 +0, lvl1 +9437184, lvl2 +11796480
// XT lives in d_out's feat region (consumed in K2, overwritten in K3):
//   lvl0 @out+655360, lvl1 @out+131072, lvl2 @out+0
// Finalize (sum halves + bias(already in half0) -> sigmoid) happens inside K2.

struct P {
    const float *sou0, *sou1, *sou2;
    const float *ref0, *ref1, *ref2;
    const float *ob0, *ob1, *ob2;
    const float *mb0, *mb1, *mb2;
    float* out;
    float* ws;
};

// ---------------- K0: fused weight repack (all levels) --------------------------------
__global__ __launch_bounds__(256) void repack_all(
    const float* __restrict__ ow0, const float* __restrict__ mw0, const float* __restrict__ rw0,
    const float* __restrict__ ow1, const float* __restrict__ mw1, const float* __restrict__ rw1,
    const float* __restrict__ ow2, const float* __restrict__ mw2, const float* __restrict__ rw2,
    float* __restrict__ dst) {
    const int lvl = blockIdx.y;
    const float* ow = lvl == 0 ? ow0 : (lvl == 1 ? ow1 : ow2);
    const float* mw = lvl == 0 ? mw0 : (lvl == 1 ? mw1 : mw2);
    const float* rw = lvl == 0 ? rw0 : (lvl == 1 ? rw1 : rw2);
    float* d = dst + lvl * 62784;
    int i = blockIdx.x * 256 + threadIdx.x;
    if (i < 18432) {  // WB: ((wvu*18+ks)*64+lane)*4+jw  (u32 = bf16 c0 | bf16 c0+1 <<16)
        int jw = i & 3;
        int lane = (i >> 2) & 63;
        int t3 = i >> 8;
        int ks = t3 % 18, wvu = t3 / 18;
        int o = wvu * 16 + (lane & 15);
        int c0 = ks * 32 + (lane >> 4) * 8 + 2 * jw;
        int g0 = c0 / 144, r0 = c0 % 144;
        int c1 = c0 + 1;
        int g1 = c1 / 144, r1 = c1 % 144;
        float w0 = rw[o * 576 + (g0 * 16 + (r0 & 15)) * 9 + (r0 >> 4)];
        float w1 = rw[o * 576 + (g1 * 16 + (r1 & 15)) * 9 + (r1 >> 4)];
        ((unsigned*)d)[i] = bf16rne(w0) | (bf16rne(w1) << 16);
    }
    if (i < 5184) {   // off -> [ic][k][18]
        int oc = i % 18, k = (i / 18) % 9, ic = i / 162;
        d[36864 + i] = ow[oc * 288 + ic * 9 + k];
    }
    if (i < 20736) {  // mod -> [ic][k][36]
        int oc = i % 36, k = (i / 36) % 9, ic = i / 324;
        d[42048 + i] = mw[oc * 576 + ic * 9 + k];
    }
}

// ---------------- K1: offset_conv(336) + mod_conv(336) + transpose(672) ---------------
// R9's 4 px/thread (72/36 FMA per load batch) PLUS ic-split x2: each conv block does
// half the input channels, writing bf16 partials. Doubles conv waves (1344->2688) at
// UNCHANGED FMA/load (R10 showed halving px halves FMA/load and regresses).
// No launch_bounds (R5/R6: bound w caps VGPR ~256/w -> spills).
__global__ __launch_bounds__(256) void k1_prep(P p) {
    __shared__ float tile[256][17];
    const int t = blockIdx.x;
    int task, i;
    if (t < 336) { task = 0; i = t; }
    else if (t < 672) { task = 1; i = t - 336; }
    else { task = 2; i = t - 672; }
    float* ws = p.ws;

    if (task == 0) {  // ---- offset conv partial: half=0 sou(+bias) / half=1 ref, 4 px/thr
        const int half = i & 1;
        const int j2 = i >> 1;  // 0..167, R9 decode
        int lvl, j;
        if (j2 < 128) { lvl = 0; j = j2; }
        else if (j2 < 160) { lvl = 1; j = j2 - 128; }
        else { lvl = 2; j = j2 - 160; }
        const int logW = 7 - lvl;
        const int W = 1 << logW, H = W, HW = H * W;
        const int nper = 16 >> (2 * lvl);
        const int qb = j % nper, g = (j / nper) & 3, b = j / (nper * 4);
        const int q = qb * 1024 + (int)threadIdx.x * 4;
        const int h = q >> logW, x0 = q & (W - 1);
        const float* src = half == 0 ? (lvl == 0 ? p.sou0 : (lvl == 1 ? p.sou1 : p.sou2))
                                     : (lvl == 0 ? p.ref0 : (lvl == 1 ? p.ref1 : p.ref2));
        const float* wt = ws + 4730880 + lvl * 62784 + 36864 + half * 16 * 162;
        const float* bias = lvl == 0 ? p.ob0 : (lvl == 1 ? p.ob1 : p.ob2);
        unsigned short* OP = (unsigned short*)ws;
        const size_t lvlOP = (lvl == 0 ? 0 : (lvl == 1 ? 2359296 : 2949120));
        float acc[4][18];
#pragma unroll
        for (int px = 0; px < 4; ++px)
#pragma unroll
            for (int u = 0; u < 18; ++u) acc[px][u] = 0.f;
        const float* base = src + (size_t)(b * 64 + g * 16) * HW;
        for (int ic = 0; ic < 16; ++ic) {
            const float* plane = base + (size_t)ic * HW;
            const float* wp = wt + ic * 162;
#pragma unroll
            for (int ky = 0; ky < 3; ++ky) {
                int yy = h + ky - 1;
                bool yok = (yy >= 0) && (yy < H);
                const float* row = plane + (size_t)min(max(yy, 0), H - 1) * W;
                float w[6];
                float4 f4 = yok ? *(const float4*)(row + x0) : make_float4(0.f, 0.f, 0.f, 0.f);
                w[0] = (yok && x0 > 0) ? row[x0 - 1] : 0.f;
                w[1] = f4.x; w[2] = f4.y; w[3] = f4.z; w[4] = f4.w;
                w[5] = (yok && x0 + 4 < W) ? row[x0 + 4] : 0.f;
#pragma unroll
                for (int kx = 0; kx < 3; ++kx) {
                    const float* wk = wp + (ky * 3 + kx) * 18;
#pragma unroll
                    for (int oc = 0; oc < 18; ++oc) {
                        float wv = wk[oc];
#pragma unroll
                        for (int px = 0; px < 4; ++px)
                            acc[px][oc] = fmaf(w[px + kx], wv, acc[px][oc]);
                    }
                }
            }
        }
        unsigned short* op = OP + half * 3096576 + lvlOP + (size_t)(b * 72 + g * 18) * HW + q;
#pragma unroll
        for (int oc = 0; oc < 18; ++oc) {
            float bb = half == 0 ? bias[oc] : 0.f;
            unsigned lo = bf16rne(acc[0][oc] + bb) | (bf16rne(acc[1][oc] + bb) << 16);
            unsigned hi = bf16rne(acc[2][oc] + bb) | (bf16rne(acc[3][oc] + bb) << 16);
            *(uint2*)&op[(size_t)oc * HW] = make_uint2(lo, hi);
        }
    } else if (task == 1) {  // ---- mod conv partial: half ic 0-31 / 32-63, wave oc-split
        const int half = i & 1;
        const int j2 = i >> 1;
        int lvl, j;
        if (j2 < 128) { lvl = 0; j = j2; }
        else if (j2 < 160) { lvl = 1; j = j2 - 128; }
        else { lvl = 2; j = j2 - 160; }
        const int logW = 7 - lvl;
        const int W = 1 << logW, H = W, HW = H * W;
        const int nper = 64 >> (2 * lvl);
        const int qb = j % nper, b = j / nper;
        const int o0 = __builtin_amdgcn_readfirstlane((int)threadIdx.x >> 6) * 9;
        const int lane = threadIdx.x & 63;
        const int q = qb * 256 + lane * 4;
        const int h = q >> logW, x0 = q & (W - 1);
        const float* sou = lvl == 0 ? p.sou0 : (lvl == 1 ? p.sou1 : p.sou2);
        const float* wt = ws + 4730880 + lvl * 62784 + 42048;
        const float* bias = lvl == 0 ? p.mb0 : (lvl == 1 ? p.mb1 : p.mb2);
        unsigned short* MP = (unsigned short*)(ws + 3096576);
        const size_t lvlMP = (lvl == 0 ? 0 : (lvl == 1 ? 1179648 : 1474560));
        float acc[4][9];
#pragma unroll
        for (int px = 0; px < 4; ++px)
#pragma unroll
            for (int u = 0; u < 9; ++u) acc[px][u] = 0.f;
        const float* base = sou + (size_t)b * 64 * HW + (size_t)(half * 32) * HW;
        for (int ic = 0; ic < 32; ++ic) {
            const float* plane = base + (size_t)ic * HW;
            const float* wp = wt + (half * 32 + ic) * 324 + o0;
#pragma unroll
            for (int ky = 0; ky < 3; ++ky) {
                int yy = h + ky - 1;
                bool yok = (yy >= 0) && (yy < H);
                const float* row = plane + (size_t)min(max(yy, 0), H - 1) * W;
                float w[6];
                float4 f4 = yok ? *(const float4*)(row + x0) : make_float4(0.f, 0.f, 0.f, 0.f);
                w[0] = (yok && x0 > 0) ? row[x0 - 1] : 0.f;
                w[1] = f4.x; w[2] = f4.y; w[3] = f4.z; w[4] = f4.w;
                w[5] = (yok && x0 + 4 < W) ? row[x0 + 4] : 0.f;
#pragma unroll
                for (int kx = 0; kx < 3; ++kx) {
                    const float* wk = wp + (ky * 3 + kx) * 36;
#pragma unroll
                    for (int oc = 0; oc < 9; ++oc) {
                        float wv = wk[oc];
#pragma unroll
                        for (int px = 0; px < 4; ++px)
                            acc[px][oc] = fmaf(w[px + kx], wv, acc[px][oc]);
                    }
                }
            }
        }
        unsigned short* mp = MP + half * 1548288 + lvlMP + (size_t)(b * 36 + o0) * HW + q;
#pragma unroll
        for (int oc = 0; oc < 9; ++oc) {
            float bb = half == 0 ? bias[o0 + oc] : 0.f;
            unsigned lo = bf16rne(acc[0][oc] + bb) | (bf16rne(acc[1][oc] + bb) << 16);
            unsigned hi = bf16rne(acc[2][oc] + bb) | (bf16rne(acc[3][oc] + bb) << 16);
            *(uint2*)&mp[(size_t)oc * HW] = make_uint2(lo, hi);
        }
    } else {  // ---- transpose (b,64,H,W) -> XT (b,g,HW,16)
        int lvl, j;
        if (i < 512) { lvl = 0; j = i; }
        else if (i < 640) { lvl = 1; j = i - 512; }
        else { lvl = 2; j = i - 640; }
        const int HW = 16384 >> (2 * lvl);
        const int nper = 64 >> (2 * lvl);
        const int qb = j % nper, g = (j / nper) & 3, b = j / (nper * 4);
        const float* sou = lvl == 0 ? p.sou0 : (lvl == 1 ? p.sou1 : p.sou2);
        float* XT = p.out + (lvl == 0 ? 655360 : (lvl == 1 ? 131072 : 0));
        const int tt = threadIdx.x;
        const int q0 = qb * 256;
        const float* src = sou + (size_t)(b * 64 + g * 16) * HW + q0;
#pragma unroll
        for (int c = 0; c < 16; ++c) tile[tt][c] = src[(size_t)c * HW + tt];
        __syncthreads();
        float4* dst = (float4*)(XT + ((size_t)(b * 4 + g) * HW + q0) * 16);
#pragma unroll
        for (int u = 0; u < 4; ++u) {
            int f4 = u * 256 + tt;
            int q = f4 >> 2, c4 = (f4 & 3) * 4;
            dst[f4] = make_float4(tile[q][c4], tile[q][c4 + 1], tile[q][c4 + 2], tile[q][c4 + 3]);
        }
    }
}

// ---------------- K2: gather(6048, finalize inline) + mean(168) -----------------------
__global__ __launch_bounds__(256) void k2_gather(P p) {
    const int t = blockIdx.x;
    float* ws = p.ws;
    const unsigned short* OP = (const unsigned short*)ws;
    const unsigned short* MP = (const unsigned short*)(ws + 3096576);
    if (t < 6048) {
        int lvl, j;
        if (t < 4608) { lvl = 0; j = t; }
        else if (t < 5760) { lvl = 1; j = t - 4608; }
        else { lvl = 2; j = t - 5760; }
        const int logW = 7 - lvl;
        const int W = 1 << logW, H = W, HW = H * W;
        const int nper = 64 >> (2 * lvl);
        const int qb = j % nper, gk = (j / nper) % 36, b = j / (nper * 36);
        const int g = gk / 9, k = gk - g * 9;
        const size_t lvlOP = (lvl == 0 ? 0 : (lvl == 1 ? 2359296 : 2949120));
        const size_t lvlMP = (lvl == 0 ? 0 : (lvl == 1 ? 1179648 : 1474560));
        const float* XT = p.out + (lvl == 0 ? 655360 : (lvl == 1 ? 131072 : 0));
        unsigned* S = (unsigned*)(ws + 4919232) + (lvl == 0 ? 0 : (lvl == 1 ? 9437184 : 11796480));
        const int q = qb * 256 + threadIdx.x;
        const int h = q >> logW, xp = q & (W - 1);
        const int ky = k / 3, kx = k - ky * 3;
        const float rng = 0.25f * (float)H;
        size_t ey = lvlOP + (size_t)(b * 72 + g * 18 + 2 * k) * HW + q;
        float vy = bf2f(OP[ey]) + bf2f(OP[ey + 3096576]);
        float vx = bf2f(OP[ey + HW]) + bf2f(OP[ey + HW + 3096576]);
        float dy = rng * (2.f * sigmoidf_(vy) - 1.f);
        float dx = rng * (2.f * sigmoidf_(vx) - 1.f);
        size_t em = lvlMP + (size_t)(b * 36 + g * 9 + k) * HW + q;
        float m = 2.f * sigmoidf_(bf2f(MP[em]) + bf2f(MP[em + 1548288]));
        float py = (float)(h - 1 + ky) + dy;
        float px = (float)(xp - 1 + kx) + dx;
        float y0f = floorf(py), x0f = floorf(px);
        float wy = py - y0f, wx = px - x0f;
        int y0 = (int)y0f, x0 = (int)x0f;
        const float* xg = XT + (size_t)(b * 4 + g) * HW * 16;
        float s[16];
#pragma unroll
        for (int c = 0; c < 16; ++c) s[c] = 0.f;
#pragma unroll
        for (int cor = 0; cor < 4; ++cor) {
            int yy = y0 + (cor >> 1), xx = x0 + (cor & 1);
            float cw = ((cor >> 1) ? wy : 1.f - wy) * ((cor & 1) ? wx : 1.f - wx);
            cw = (yy >= 0 && yy < H && xx >= 0 && xx < W) ? cw * m : 0.f;
            int yc = min(max(yy, 0), H - 1), xc = min(max(xx, 0), W - 1);
            const float4* pp = (const float4*)(xg + (size_t)((yc << logW) + xc) * 16);
            float4 v0 = pp[0], v1 = pp[1], v2 = pp[2], v3 = pp[3];
            s[0] = fmaf(cw, v0.x, s[0]);   s[1] = fmaf(cw, v0.y, s[1]);
            s[2] = fmaf(cw, v0.z, s[2]);   s[3] = fmaf(cw, v0.w, s[3]);
            s[4] = fmaf(cw, v1.x, s[4]);   s[5] = fmaf(cw, v1.y, s[5]);
            s[6] = fmaf(cw, v1.z, s[6]);   s[7] = fmaf(cw, v1.w, s[7]);
            s[8] = fmaf(cw, v2.x, s[8]);   s[9] = fmaf(cw, v2.y, s[9]);
            s[10] = fmaf(cw, v2.z, s[10]); s[11] = fmaf(cw, v2.w, s[11]);
            s[12] = fmaf(cw, v3.x, s[12]); s[13] = fmaf(cw, v3.y, s[13]);
            s[14] = fmaf(cw, v3.z, s[14]); s[15] = fmaf(cw, v3.w, s[15]);
        }
        unsigned* Sp = S + (size_t)(b * 288 + gk * 8) * HW + q;
#pragma unroll
        for (int pr = 0; pr < 8; ++pr) {
            unsigned u = bf16rne(s[2 * pr]) | (bf16rne(s[2 * pr + 1]) << 16);
            Sp[(size_t)pr * HW] = u;
        }
    } else {
        int i = t - 6048;
        int lvl, j;
        if (i < 128) { lvl = 0; j = i; }
        else if (i < 160) { lvl = 1; j = i - 128; }
        else { lvl = 2; j = i - 160; }
        const int HW = 16384 >> (2 * lvl);
        const int nper = 64 >> (2 * lvl);
        const int qb = j % nper, b = j / nper;
        const size_t lvlOP = (lvl == 0 ? 0 : (lvl == 1 ? 2359296 : 2949120));
        float* MEAN = ws + (lvl == 0 ? 4644864 : (lvl == 1 ? 4710400 : 4726784));
        const float rng = 0.25f * (float)(128 >> lvl);
        const int q = qb * 256 + threadIdx.x;
        const unsigned short* pp = OP + lvlOP + (size_t)b * 72 * HW + q;
        float sy = 0.f, sx = 0.f;
#pragma unroll
        for (int u = 0; u < 36; ++u) {
            size_t e = (size_t)(2 * u) * HW;
            float vy = bf2f(pp[e]) + bf2f(pp[e + 3096576]);
            float vx = bf2f(pp[e + HW]) + bf2f(pp[e + HW + 3096576]);
            sy += rng * (2.f * sigmoidf_(vy) - 1.f);
            sx += rng * (2.f * sigmoidf_(vx) - 1.f);
        }
        MEAN[(size_t)(b * 2) * HW + q] = sy * (1.f / 36.f);
        MEAN[(size_t)(b * 2 + 1) * HW + q] = sx * (1.f / 36.f);
    }
}

// ---------------- K3: MFMA dgemm(672, 2x144-row LDS chunks) + upsample(3072) ----------
__global__ __launch_bounds__(256) void k3_out(P p) {
    __shared__ unsigned lds[144 * 64];  // 36 KB -> 4 blocks/CU
    const int t = blockIdx.x;
    float* ws = p.ws;
    if (t < 672) {
        int lvl, j;
        if (t < 512) { lvl = 0; j = t; }
        else if (t < 640) { lvl = 1; j = t - 512; }
        else { lvl = 2; j = t - 640; }
        const int HW = 16384 >> (2 * lvl);
        const int nper = 256 >> (2 * lvl);
        const int qb = j % nper, b = j / nper;
        const unsigned* S = (const unsigned*)(ws + 4919232) +
                            (lvl == 0 ? 0 : (lvl == 1 ? 9437184 : 11796480));
        const unsigned* WB = (const unsigned*)(ws + 4730880 + lvl * 62784);
        float* outp = p.out + (lvl == 0 ? 655360 : (lvl == 1 ? 131072 : 0));
        const int q0 = qb * 64;
        const int tid = threadIdx.x;
        const int wvu = __builtin_amdgcn_readfirstlane(tid >> 6);
        const int lane = tid & 63;
        const int quad = lane >> 4, lo16 = lane & 15;
        union U { uint4 u; int4 i; short8 s; f32x4 f; };
        f32x4 acc[4];
#pragma unroll
        for (int mt = 0; mt < 4; ++mt) acc[mt] = (f32x4){0.f, 0.f, 0.f, 0.f};
        for (int chk = 0; chk < 2; ++chk) {
            __syncthreads();
            const unsigned* Sb = S + (size_t)(b * 288 + chk * 144) * HW + q0;
            for (int i = tid; i < 144 * 16; i += 256) {
                int r = i >> 4, ch = (i & 15) << 2;
                *(uint4*)&lds[r * 64 + ch] = *(const uint4*)(Sb + (size_t)r * HW + ch);
            }
            __syncthreads();
            uint4 bfr[9];
#pragma unroll
            for (int k9 = 0; k9 < 9; ++k9)
                bfr[k9] = *(const uint4*)(WB + (((wvu * 18 + chk * 9 + k9) * 64 + lane) << 2));
#pragma unroll
            for (int k9 = 0; k9 < 9; ++k9) {
                const int rb = k9 * 16 + quad * 4;
                U bu; bu.u = bfr[k9];
#pragma unroll
                for (int mt = 0; mt < 4; ++mt) {
                    const int px = mt * 16 + lo16;
                    U au;
                    au.i.x = (int)lds[(rb + 0) * 64 + px];
                    au.i.y = (int)lds[(rb + 1) * 64 + px];
                    au.i.z = (int)lds[(rb + 2) * 64 + px];
                    au.i.w = (int)lds[(rb + 3) * 64 + px];
                    acc[mt] = __builtin_amdgcn_mfma_f32_16x16x32_bf16(au.s, bu.s, acc[mt], 0, 0, 0);
                }
            }
        }
        float* op = outp + (size_t)(b * 64 + wvu * 16 + lo16) * HW + q0;
#pragma unroll
        for (int mt = 0; mt < 4; ++mt)
#pragma unroll
            for (int rg = 0; rg < 4; ++rg)
                op[mt * 16 + quad * 4 + rg] = acc[mt][rg];
    } else {
        // upsample: 4 px/thread over flat [lvl][b][c][512][512]
        int i = t - 672;  // 0..3071
        int flat = (i * 256 + (int)threadIdx.x) * 4;
        int lvl = flat >> 20;
        int r = flat & 1048575;
        int b = r >> 19, c = (r >> 18) & 1;
        int pix = r & 262143;
        int yo = pix >> 9, xo = pix & 511;
        const int H = 128 >> lvl, W = H;
        const float* MEAN = ws + (lvl == 0 ? 4644864 : (lvl == 1 ? 4710400 : 4726784));
        const float* m = MEAN + (size_t)(b * 2 + c) * H * W;
        float* o = p.out + (lvl == 0 ? 4849664 : (lvl == 1 ? 3801088 : 2752512)) +
                   ((size_t)(b * 2 + c) * 512 + yo) * 512 + xo;
        const float fs = (float)(4 << lvl);
        const float sc = (float)(H - 1) * (1.f / 511.f);
        float sy = yo * sc;
        int y0 = min((int)sy, H - 2);
        float wy = sy - (float)y0;
        float rr[4];
#pragma unroll
        for (int u = 0; u < 4; ++u) {
            float sx = (float)(xo + u) * sc;
            int x0 = min((int)sx, W - 2);
            float wx = sx - (float)x0;
            float v00 = m[y0 * W + x0], v01 = m[y0 * W + x0 + 1];
            float v10 = m[(y0 + 1) * W + x0], v11 = m[(y0 + 1) * W + x0 + 1];
            float r0 = v00 * (1.f - wy) + v10 * wy;
            float r1 = v01 * (1.f - wy) + v11 * wy;
            rr[u] = (r0 * (1.f - wx) + r1 * wx) * fs;
        }
        *(float4*)o = make_float4(rr[0], rr[1], rr[2], rr[3]);
    }
}

extern "C" void kernel_launch(void* const* d_in, const int* in_sizes, int n_in,
                              void* d_out, int out_size, void* d_ws, size_t ws_size,
                              hipStream_t stream) {
    const float* fin[21];
    for (int i = 0; i < 21; ++i) fin[i] = (const float*)d_in[i];
    P p;
    if (in_sizes[1] == in_sizes[0]) {  // dict order sou1,ref1,sou2,ref2,sou3,ref3
        p.sou0 = fin[0]; p.ref0 = fin[1];
        p.sou1 = fin[2]; p.ref1 = fin[3];
        p.sou2 = fin[4]; p.ref2 = fin[5];
    } else {  // arg order
        p.sou0 = fin[0]; p.sou1 = fin[1]; p.sou2 = fin[2];
        p.ref0 = fin[3]; p.ref1 = fin[4]; p.ref2 = fin[5];
    }
    p.ob0 = fin[7]; p.mb0 = fin[9];
    p.ob1 = fin[12]; p.mb1 = fin[14];
    p.ob2 = fin[17]; p.mb2 = fin[19];
    p.out = (float*)d_out;
    p.ws = (float*)d_ws;

    repack_all<<<dim3(144, 3), 256, 0, stream>>>(
        fin[6], fin[8], fin[10], fin[11], fin[13], fin[15], fin[16], fin[18], fin[20],
        p.ws + 4730880);
    k1_prep<<<dim3(1344), 256, 0, stream>>>(p);
    k2_gather<<<dim3(6216), 256, 0, stream>>>(p);
    k3_out<<<dim3(3744), 256, 0, stream>>>(p);
}

// Round 12
// 230.492 us; speedup vs baseline: 1.5541x; 1.2878x over previous
//
#include <hip/hip_runtime.h>

typedef __attribute__((ext_vector_type(8))) short short8;
typedef __attribute__((ext_vector_type(4))) float f32x4;

__device__ __forceinline__ float sigmoidf_(float x) { return 1.f / (1.f + __expf(-x)); }
__device__ __forceinline__ unsigned bf16rne(float x) {
    unsigned b = __float_as_uint(x);
    return (b + 0x7FFFu + ((b >> 16) & 1u)) >> 16;
}

// ws layout (float words)  [R9 layout restored]:
//   OFFM:  lvl0 @0 (2359296), lvl1 @2359296 (589824), lvl2 @2949120 (147456)
//   MOD:   lvl0 @3096576 (1179648), lvl1 @4276224 (294912), lvl2 @4571136 (73728)
//   MEAN:  lvl0 @4644864 (65536), lvl1 @4710400 (16384), lvl2 @4726784 (4096)
//   WREP:  @4730880, 3*62784 floats; per lvl as u32:
//          [0..18432)  WB  dgemm B-frags
//          [36864..41472) WBO offset-conv B-frags (taps9 x nt2, oc>=18 zeroed)
//          [41472..55296) WBM mod-conv B-frags (taps9 x chunk2 x nt3, oc>=36 zeroed)
//   S:     @4919232 (uints), lvl0 +0, lvl1 +9437184, lvl2 +11796480
// XT lives in d_out's feat region (consumed in K2, overwritten in K3):
//   lvl0 @out+655360, lvl1 @out+131072, lvl2 @out+0

struct P {
    const float *sou0, *sou1, *sou2;
    const float *ref0, *ref1, *ref2;
    const float *ob0, *ob1, *ob2;
    const float *mb0, *mb1, *mb2;
    float* out;
    float* ws;
};

union U {
    uint4 u4; int4 i4; short8 s8; f32x4 f4;
};

// ---------------- K0: fused weight repack (all levels) --------------------------------
// B-frag convention (verified via k3/R9): B[n][k], n = nt*16 + (lane&15),
// k = (lane>>4)*8 + j within 32-chunk; u32 jw packs j=2jw (lo) / 2jw+1 (hi).
__global__ __launch_bounds__(256) void repack_all(
    const float* __restrict__ ow0, const float* __restrict__ mw0, const float* __restrict__ rw0,
    const float* __restrict__ ow1, const float* __restrict__ mw1, const float* __restrict__ rw1,
    const float* __restrict__ ow2, const float* __restrict__ mw2, const float* __restrict__ rw2,
    float* __restrict__ dst) {
    const int lvl = blockIdx.y;
    const float* ow = lvl == 0 ? ow0 : (lvl == 1 ? ow1 : ow2);
    const float* mw = lvl == 0 ? mw0 : (lvl == 1 ? mw1 : mw2);
    const float* rw = lvl == 0 ? rw0 : (lvl == 1 ? rw1 : rw2);
    unsigned* d = (unsigned*)(dst + lvl * 62784);
    int i = blockIdx.x * 256 + threadIdx.x;
    if (i < 18432) {  // WB (dgemm): ((wvu*18+ks)*64+lane)*4+jw
        int jw = i & 3;
        int lane = (i >> 2) & 63;
        int t3 = i >> 8;
        int ks = t3 % 18, wvu = t3 / 18;
        int o = wvu * 16 + (lane & 15);
        int c0 = ks * 32 + (lane >> 4) * 8 + 2 * jw;
        int g0 = c0 / 144, r0 = c0 % 144;
        int c1 = c0 + 1;
        int g1 = c1 / 144, r1 = c1 % 144;
        float w0 = rw[o * 576 + (g0 * 16 + (r0 & 15)) * 9 + (r0 >> 4)];
        float w1 = rw[o * 576 + (g1 * 16 + (r1 & 15)) * 9 + (r1 >> 4)];
        d[i] = bf16rne(w0) | (bf16rne(w1) << 16);
    } else if (i < 23040) {  // WBO: ((tap*2+nt)*64+lane)*4+jw ; K = ic (32: sou16|ref16)
        int o2 = i - 18432;
        int jw = o2 & 3;
        int lane = (o2 >> 2) & 63;
        int t2 = o2 >> 8;           // 0..17
        int tap = t2 >> 1, nt = t2 & 1;
        int n = nt * 16 + (lane & 15);
        int ic0 = (lane >> 4) * 8 + 2 * jw;
        float w0 = (n < 18) ? ow[n * 288 + ic0 * 9 + tap] : 0.f;
        float w1 = (n < 18) ? ow[n * 288 + (ic0 + 1) * 9 + tap] : 0.f;
        d[36864 + o2] = bf16rne(w0) | (bf16rne(w1) << 16);
    } else if (i < 36864) {  // WBM: (((tap*2+c)*3+nt)*64+lane)*4+jw ; K = ic (64)
        int o3 = i - 23040;
        int jw = o3 & 3;
        int lane = (o3 >> 2) & 63;
        int t3 = o3 >> 8;           // 0..53
        int nt = t3 % 3, tc = t3 / 3;
        int tap = tc >> 1, c = tc & 1;
        int n = nt * 16 + (lane & 15);
        int ic0 = c * 32 + (lane >> 4) * 8 + 2 * jw;
        float w0 = (n < 36) ? mw[n * 576 + ic0 * 9 + tap] : 0.f;
        float w1 = (n < 36) ? mw[n * 576 + (ic0 + 1) * 9 + tap] : 0.f;
        d[41472 + o3] = bf16rne(w0) | (bf16rne(w1) << 16);
    }
}

// ---------------- K1: MFMA offset_conv(2688) + MFMA mod_conv(672) + transpose(672) ----
// Conv-as-GEMM: 64-px block, 3x3 halo tile staged in LDS as [pixel][channel] bf16
// (ICpad 40/72 keeps ds_read_b128 16B-aligned). A-frag = 1 ds_read_b128 per
// (tap,chunk,wave); B-frags pre-packed by K0. Waves split M (16 px each).
// R7-R11 showed VALU conv plateaus ~125us (latency-bound at 2.6 blk/CU); MFMA moves
// the 2.7 GFLOP to the matrix pipe. No launch_bounds (R5/R6 spill lesson).
__global__ __launch_bounds__(256) void k1_prep(P p) {
    __shared__ __align__(16) char smem[28512];  // max(198*72, 198*40, 256*17*4/..)*2
    const int t = blockIdx.x;
    float* ws = p.ws;
    const int tid = threadIdx.x;

    if (t < 2688) {  // ---- offset conv GEMM: per (b,g), 32ch -> 18(pad 32), K=288
        int lvl, j;
        if (t < 2048) { lvl = 0; j = t; }
        else if (t < 2560) { lvl = 1; j = t - 2048; }
        else { lvl = 2; j = t - 2560; }
        const int logW = 7 - lvl;
        const int W = 1 << logW, H = W, HW = H * W;
        const int nper = 256 >> (2 * lvl);
        const int qb = j % nper, g = (j / nper) & 3, b = j / (nper * 4);
        const int q0 = qb * 64;
        const int hlo = q0 >> logW;
        const int xlo = q0 & (W - 1);
        const int cols = (W >= 64) ? 66 : 34;
        const int rcTot = (W >= 64) ? 198 : 136;  // rowsN*cols
        const float* sou = lvl == 0 ? p.sou0 : (lvl == 1 ? p.sou1 : p.sou2);
        const float* ref = lvl == 0 ? p.ref0 : (lvl == 1 ? p.ref1 : p.ref2);
        const float* bases = sou + (size_t)(b * 64 + g * 16) * HW;
        const float* baser = ref + (size_t)(b * 64 + g * 16) * HW;
        unsigned* ldsW = (unsigned*)smem;  // dword view, row stride 20 dw (40 shorts)
        // stage: rc = tid (<=198 < 256), 32 channels, 2 per iteration
        const bool sact = tid < rcTot;
        const int srow = tid / cols, scol = tid - srow * cols;
        const int grow = hlo - 1 + srow, gcol = xlo - 1 + scol;
        const bool inb = sact && grow >= 0 && grow < H && gcol >= 0 && gcol < W;
        const size_t goff = inb ? ((size_t)grow * W + gcol) : 0;
#pragma unroll
        for (int ic = 0; ic < 32; ic += 2) {
            float v0 = 0.f, v1 = 0.f;
            if (inb) {
                const float* p0 = (ic < 16) ? bases + (size_t)ic * HW
                                            : baser + (size_t)(ic - 16) * HW;
                v0 = p0[goff]; v1 = p0[HW + goff];
            }
            if (sact) ldsW[tid * 20 + (ic >> 1)] = bf16rne(v0) | (bf16rne(v1) << 16);
        }
        __syncthreads();
        const int wvu = __builtin_amdgcn_readfirstlane(tid >> 6);
        const int lane = tid & 63, quad = lane >> 4, lo16 = lane & 15;
        const int qg = q0 + wvu * 16 + lo16;
        const int rowB = (qg >> logW) - hlo;
        const int colB = (qg & (W - 1)) - xlo;
        const unsigned short* ldsS = (const unsigned short*)smem;
        const unsigned* WBO = (const unsigned*)(ws + 4730880 + lvl * 62784) + 36864;
        f32x4 acc[2];
        acc[0] = (f32x4){0.f, 0.f, 0.f, 0.f};
        acc[1] = (f32x4){0.f, 0.f, 0.f, 0.f};
#pragma unroll
        for (int tap = 0; tap < 9; ++tap) {
            const int ky = tap / 3, kx = tap - ky * 3;
            const int rc = (rowB + ky) * cols + colB + kx;
            U au; au.s8 = *(const short8*)&ldsS[rc * 40 + quad * 8];
#pragma unroll
            for (int nt = 0; nt < 2; ++nt) {
                U bu; bu.u4 = *(const uint4*)(WBO + ((tap * 2 + nt) * 64 + lane) * 4);
                acc[nt] = __builtin_amdgcn_mfma_f32_16x16x32_bf16(au.s8, bu.s8, acc[nt], 0, 0, 0);
            }
        }
        const float* bias = lvl == 0 ? p.ob0 : (lvl == 1 ? p.ob1 : p.ob2);
        float* OFFM = ws + (lvl == 0 ? 0 : (lvl == 1 ? 2359296 : 2949120));
        const float rng = 0.25f * (float)H;
#pragma unroll
        for (int nt = 0; nt < 2; ++nt) {
            const int o = nt * 16 + lo16;
            if (o < 18) {
                const float bb = bias[o];
                float* op = OFFM + (size_t)(b * 72 + g * 18 + o) * HW + q0 + wvu * 16 + quad * 4;
#pragma unroll
                for (int rg = 0; rg < 4; ++rg)
                    op[rg] = rng * (2.f * sigmoidf_(acc[nt][rg] + bb) - 1.f);
            }
        }
    } else if (t < 3360) {  // ---- mod conv GEMM: 64ch -> 36(pad 48), K=576
        const int i1 = t - 2688;
        int lvl, j;
        if (i1 < 512) { lvl = 0; j = i1; }
        else if (i1 < 640) { lvl = 1; j = i1 - 512; }
        else { lvl = 2; j = i1 - 640; }
        const int logW = 7 - lvl;
        const int W = 1 << logW, H = W, HW = H * W;
        const int nper = 256 >> (2 * lvl);
        const int qb = j % nper, b = j / nper;
        const int q0 = qb * 64;
        const int hlo = q0 >> logW;
        const int xlo = q0 & (W - 1);
        const int cols = (W >= 64) ? 66 : 34;
        const int rcTot = (W >= 64) ? 198 : 136;
        const float* sou = lvl == 0 ? p.sou0 : (lvl == 1 ? p.sou1 : p.sou2);
        const float* base = sou + (size_t)b * 64 * HW;
        unsigned* ldsW = (unsigned*)smem;  // row stride 36 dw (72 shorts)
        const bool sact = tid < rcTot;
        const int srow = tid / cols, scol = tid - srow * cols;
        const int grow = hlo - 1 + srow, gcol = xlo - 1 + scol;
        const bool inb = sact && grow >= 0 && grow < H && gcol >= 0 && gcol < W;
        const size_t goff = inb ? ((size_t)grow * W + gcol) : 0;
#pragma unroll
        for (int ic = 0; ic < 64; ic += 2) {
            float v0 = 0.f, v1 = 0.f;
            if (inb) {
                const float* p0 = base + (size_t)ic * HW;
                v0 = p0[goff]; v1 = p0[HW + goff];
            }
            if (sact) ldsW[tid * 36 + (ic >> 1)] = bf16rne(v0) | (bf16rne(v1) << 16);
        }
        __syncthreads();
        const int wvu = __builtin_amdgcn_readfirstlane(tid >> 6);
        const int lane = tid & 63, quad = lane >> 4, lo16 = lane & 15;
        const int qg = q0 + wvu * 16 + lo16;
        const int rowB = (qg >> logW) - hlo;
        const int colB = (qg & (W - 1)) - xlo;
        const unsigned short* ldsS = (const unsigned short*)smem;
        const unsigned* WBM = (const unsigned*)(ws + 4730880 + lvl * 62784) + 41472;
        f32x4 acc[3];
        acc[0] = (f32x4){0.f, 0.f, 0.f, 0.f};
        acc[1] = (f32x4){0.f, 0.f, 0.f, 0.f};
        acc[2] = (f32x4){0.f, 0.f, 0.f, 0.f};
#pragma unroll
        for (int tap = 0; tap < 9; ++tap) {
            const int ky = tap / 3, kx = tap - ky * 3;
            const int rc = (rowB + ky) * cols + colB + kx;
#pragma unroll
            for (int c = 0; c < 2; ++c) {
                U au; au.s8 = *(const short8*)&ldsS[rc * 72 + c * 32 + quad * 8];
#pragma unroll
                for (int nt = 0; nt < 3; ++nt) {
                    U bu;
                    bu.u4 = *(const uint4*)(WBM + (((tap * 2 + c) * 3 + nt) * 64 + lane) * 4);
                    acc[nt] = __builtin_amdgcn_mfma_f32_16x16x32_bf16(au.s8, bu.s8, acc[nt], 0, 0, 0);
                }
            }
        }
        const float* bias = lvl == 0 ? p.mb0 : (lvl == 1 ? p.mb1 : p.mb2);
        float* MOD = ws + (lvl == 0 ? 3096576 : (lvl == 1 ? 4276224 : 4571136));
#pragma unroll
        for (int nt = 0; nt < 3; ++nt) {
            const int o = nt * 16 + lo16;
            if (o < 36) {
                const float bb = bias[o];
                float* op = MOD + (size_t)(b * 36 + o) * HW + q0 + wvu * 16 + quad * 4;
#pragma unroll
                for (int rg = 0; rg < 4; ++rg)
                    op[rg] = 2.f * sigmoidf_(acc[nt][rg] + bb);
            }
        }
    } else {  // ---- transpose (b,64,H,W) -> XT (b,g,HW,16)
        const int i2 = t - 3360;
        int lvl, j;
        if (i2 < 512) { lvl = 0; j = i2; }
        else if (i2 < 640) { lvl = 1; j = i2 - 512; }
        else { lvl = 2; j = i2 - 640; }
        const int HW = 16384 >> (2 * lvl);
        const int nper = 64 >> (2 * lvl);
        const int qb = j % nper, g = (j / nper) & 3, b = j / (nper * 4);
        const float* sou = lvl == 0 ? p.sou0 : (lvl == 1 ? p.sou1 : p.sou2);
        float* XT = p.out + (lvl == 0 ? 655360 : (lvl == 1 ? 131072 : 0));
        float (*tile)[17] = (float(*)[17])smem;  // 256x17x4 = 17408 <= 28512
        const int q0 = qb * 256;
        const float* src = sou + (size_t)(b * 64 + g * 16) * HW + q0;
        // NOTE: 256x17 floats = 17408 B fits smem; threads stage 16 ch of 256 px
#pragma unroll
        for (int c = 0; c < 16; ++c) tile[tid][c] = src[(size_t)c * HW + tid];
        __syncthreads();
        float4* dst = (float4*)(XT + ((size_t)(b * 4 + g) * HW + q0) * 16);
#pragma unroll
        for (int u = 0; u < 4; ++u) {
            int f4 = u * 256 + tid;
            int q = f4 >> 2, c4 = (f4 & 3) * 4;
            dst[f4] = make_float4(tile[q][c4], tile[q][c4 + 1], tile[q][c4 + 2], tile[q][c4 + 3]);
        }
    }
}

// ---------------- K2: gather(6048) + mean(168)  [R9 form] -----------------------------
__global__ __launch_bounds__(256) void k2_gather(P p) {
    const int t = blockIdx.x;
    float* ws = p.ws;
    if (t < 6048) {
        int lvl, j;
        if (t < 4608) { lvl = 0; j = t; }
        else if (t < 5760) { lvl = 1; j = t - 4608; }
        else { lvl = 2; j = t - 5760; }
        const int logW = 7 - lvl;
        const int W = 1 << logW, H = W, HW = H * W;
        const int nper = 64 >> (2 * lvl);
        const int qb = j % nper, gk = (j / nper) % 36, b = j / (nper * 36);
        const int g = gk / 9, k = gk - g * 9;
        const float* OFFM = ws + (lvl == 0 ? 0 : (lvl == 1 ? 2359296 : 2949120));
        const float* MOD = ws + (lvl == 0 ? 3096576 : (lvl == 1 ? 4276224 : 4571136));
        const float* XT = p.out + (lvl == 0 ? 655360 : (lvl == 1 ? 131072 : 0));
        unsigned* S = (unsigned*)(ws + 4919232) + (lvl == 0 ? 0 : (lvl == 1 ? 9437184 : 11796480));
        const int q = qb * 256 + threadIdx.x;
        const int h = q >> logW, xp = q & (W - 1);
        const int ky = k / 3, kx = k - ky * 3;
        float dy = OFFM[(size_t)(b * 72 + g * 18 + 2 * k) * HW + q];
        float dx = OFFM[(size_t)(b * 72 + g * 18 + 2 * k + 1) * HW + q];
        float m = MOD[(size_t)(b * 36 + g * 9 + k) * HW + q];
        float py = (float)(h - 1 + ky) + dy;
        float px = (float)(xp - 1 + kx) + dx;
        float y0f = floorf(py), x0f = floorf(px);
        float wy = py - y0f, wx = px - x0f;
        int y0 = (int)y0f, x0 = (int)x0f;
        const float* xg = XT + (size_t)(b * 4 + g) * HW * 16;
        float s[16];
#pragma unroll
        for (int c = 0; c < 16; ++c) s[c] = 0.f;
#pragma unroll
        for (int cor = 0; cor < 4; ++cor) {
            int yy = y0 + (cor >> 1), xx = x0 + (cor & 1);
            float cw = ((cor >> 1) ? wy : 1.f - wy) * ((cor & 1) ? wx : 1.f - wx);
            cw = (yy >= 0 && yy < H && xx >= 0 && xx < W) ? cw * m : 0.f;
            int yc = min(max(yy, 0), H - 1), xc = min(max(xx, 0), W - 1);
            const float4* pp = (const float4*)(xg + (size_t)((yc << logW) + xc) * 16);
            float4 v0 = pp[0], v1 = pp[1], v2 = pp[2], v3 = pp[3];
            s[0] = fmaf(cw, v0.x, s[0]);   s[1] = fmaf(cw, v0.y, s[1]);
            s[2] = fmaf(cw, v0.z, s[2]);   s[3] = fmaf(cw, v0.w, s[3]);
            s[4] = fmaf(cw, v1.x, s[4]);   s[5] = fmaf(cw, v1.y, s[5]);
            s[6] = fmaf(cw, v1.z, s[6]);   s[7] = fmaf(cw, v1.w, s[7]);
            s[8] = fmaf(cw, v2.x, s[8]);   s[9] = fmaf(cw, v2.y, s[9]);
            s[10] = fmaf(cw, v2.z, s[10]); s[11] = fmaf(cw, v2.w, s[11]);
            s[12] = fmaf(cw, v3.x, s[12]); s[13] = fmaf(cw, v3.y, s[13]);
            s[14] = fmaf(cw, v3.z, s[14]); s[15] = fmaf(cw, v3.w, s[15]);
        }
        unsigned* Sp = S + (size_t)(b * 288 + gk * 8) * HW + q;
#pragma unroll
        for (int pr = 0; pr < 8; ++pr) {
            unsigned u = bf16rne(s[2 * pr]) | (bf16rne(s[2 * pr + 1]) << 16);
            Sp[(size_t)pr * HW] = u;
        }
    } else {
        int i = t - 6048;
        int lvl, j;
        if (i < 128) { lvl = 0; j = i; }
        else if (i < 160) { lvl = 1; j = i - 128; }
        else { lvl = 2; j = i - 160; }
        const int HW = 16384 >> (2 * lvl);
        const int nper = 64 >> (2 * lvl);
        const int qb = j % nper, b = j / nper;
        const float* OFFM = ws + (lvl == 0 ? 0 : (lvl == 1 ? 2359296 : 2949120));
        float* MEAN = ws + (lvl == 0 ? 4644864 : (lvl == 1 ? 4710400 : 4726784));
        const int q = qb * 256 + threadIdx.x;
        const float* pp = OFFM + (size_t)b * 72 * HW + q;
        float sy = 0.f, sx = 0.f;
#pragma unroll
        for (int u = 0; u < 36; ++u) {
            sy += pp[(size_t)(2 * u) * HW];
            sx += pp[(size_t)(2 * u + 1) * HW];
        }
        MEAN[(size_t)(b * 2) * HW + q] = sy * (1.f / 36.f);
        MEAN[(size_t)(b * 2 + 1) * HW + q] = sx * (1.f / 36.f);
    }
}

// ---------------- K3: MFMA dgemm(672, 2x144-row LDS chunks) + upsample(3072) ----------
__global__ __launch_bounds__(256) void k3_out(P p) {
    __shared__ unsigned lds[144 * 64];  // 36 KB -> 4 blocks/CU
    const int t = blockIdx.x;
    float* ws = p.ws;
    if (t < 672) {
        int lvl, j;
        if (t < 512) { lvl = 0; j = t; }
        else if (t < 640) { lvl = 1; j = t - 512; }
        else { lvl = 2; j = t - 640; }
        const int HW = 16384 >> (2 * lvl);
        const int nper = 256 >> (2 * lvl);
        const int qb = j % nper, b = j / nper;
        const unsigned* S = (const unsigned*)(ws + 4919232) +
                            (lvl == 0 ? 0 : (lvl == 1 ? 9437184 : 11796480));
        const unsigned* WB = (const unsigned*)(ws + 4730880 + lvl * 62784);
        float* outp = p.out + (lvl == 0 ? 655360 : (lvl == 1 ? 131072 : 0));
        const int q0 = qb * 64;
        const int tid = threadIdx.x;
        const int wvu = __builtin_amdgcn_readfirstlane(tid >> 6);
        const int lane = tid & 63;
        const int quad = lane >> 4, lo16 = lane & 15;
        f32x4 acc[4];
#pragma unroll
        for (int mt = 0; mt < 4; ++mt) acc[mt] = (f32x4){0.f, 0.f, 0.f, 0.f};
        for (int chk = 0; chk < 2; ++chk) {
            __syncthreads();
            const unsigned* Sb = S + (size_t)(b * 288 + chk * 144) * HW + q0;
            for (int i = tid; i < 144 * 16; i += 256) {
                int r = i >> 4, ch = (i & 15) << 2;
                *(uint4*)&lds[r * 64 + ch] = *(const uint4*)(Sb + (size_t)r * HW + ch);
            }
            __syncthreads();
            uint4 bfr[9];
#pragma unroll
            for (int k9 = 0; k9 < 9; ++k9)
                bfr[k9] = *(const uint4*)(WB + (((wvu * 18 + chk * 9 + k9) * 64 + lane) << 2));
#pragma unroll
            for (int k9 = 0; k9 < 9; ++k9) {
                const int rb = k9 * 16 + quad * 4;
                U bu; bu.u4 = bfr[k9];
#pragma unroll
                for (int mt = 0; mt < 4; ++mt) {
                    const int px = mt * 16 + lo16;
                    U au;
                    au.i4.x = (int)lds[(rb + 0) * 64 + px];
                    au.i4.y = (int)lds[(rb + 1) * 64 + px];
                    au.i4.z = (int)lds[(rb + 2) * 64 + px];
                    au.i4.w = (int)lds[(rb + 3) * 64 + px];
                    acc[mt] = __builtin_amdgcn_mfma_f32_16x16x32_bf16(au.s8, bu.s8, acc[mt], 0, 0, 0);
                }
            }
        }
        float* op = outp + (size_t)(b * 64 + wvu * 16 + lo16) * HW + q0;
#pragma unroll
        for (int mt = 0; mt < 4; ++mt)
#pragma unroll
            for (int rg = 0; rg < 4; ++rg)
                op[mt * 16 + quad * 4 + rg] = acc[mt][rg];
    } else {
        // upsample: 4 px/thread over flat [lvl][b][c][512][512]
        int i = t - 672;  // 0..3071
        int flat = (i * 256 + (int)threadIdx.x) * 4;
        int lvl = flat >> 20;
        int r = flat & 1048575;
        int b = r >> 19, c = (r >> 18) & 1;
        int pix = r & 262143;
        int yo = pix >> 9, xo = pix & 511;
        const int H = 128 >> lvl, W = H;
        const float* MEAN = ws + (lvl == 0 ? 4644864 : (lvl == 1 ? 4710400 : 4726784));
        const float* m = MEAN + (size_t)(b * 2 + c) * H * W;
        float* o = p.out + (lvl == 0 ? 4849664 : (lvl == 1 ? 3801088 : 2752512)) +
                   ((size_t)(b * 2 + c) * 512 + yo) * 512 + xo;
        const float fs = (float)(4 << lvl);
        const float sc = (float)(H - 1) * (1.f / 511.f);
        float sy = yo * sc;
        int y0 = min((int)sy, H - 2);
        float wy = sy - (float)y0;
        float rr[4];
#pragma unroll
        for (int u = 0; u < 4; ++u) {
            float sx = (float)(xo + u) * sc;
            int x0 = min((int)sx, W - 2);
            float wx = sx - (float)x0;
            float v00 = m[y0 * W + x0], v01 = m[y0 * W + x0 + 1];
            float v10 = m[(y0 + 1) * W + x0], v11 = m[(y0 + 1) * W + x0 + 1];
            float r0 = v00 * (1.f - wy) + v10 * wy;
            float r1 = v01 * (1.f - wy) + v11 * wy;
            rr[u] = (r0 * (1.f - wx) + r1 * wx) * fs;
        }
        *(float4*)o = make_float4(rr[0], rr[1], rr[2], rr[3]);
    }
}

extern "C" void kernel_launch(void* const* d_in, const int* in_sizes, int n_in,
                              void* d_out, int out_size, void* d_ws, size_t ws_size,
                              hipStream_t stream) {
    const float* fin[21];
    for (int i = 0; i < 21; ++i) fin[i] = (const float*)d_in[i];
    P p;
    if (in_sizes[1] == in_sizes[0]) {  // dict order sou1,ref1,sou2,ref2,sou3,ref3
        p.sou0 = fin[0]; p.ref0 = fin[1];
        p.sou1 = fin[2]; p.ref1 = fin[3];
        p.sou2 = fin[4]; p.ref2 = fin[5];
    } else {  // arg order
        p.sou0 = fin[0]; p.sou1 = fin[1]; p.sou2 = fin[2];
        p.ref0 = fin[3]; p.ref1 = fin[4]; p.ref2 = fin[5];
    }
    p.ob0 = fin[7]; p.mb0 = fin[9];
    p.ob1 = fin[12]; p.mb1 = fin[14];
    p.ob2 = fin[17]; p.mb2 = fin[19];
    p.out = (float*)d_out;
    p.ws = (float*)d_ws;

    repack_all<<<dim3(144, 3), 256, 0, stream>>>(
        fin[6], fin[8], fin[10], fin[11], fin[13], fin[15], fin[16], fin[18], fin[20],
        p.ws + 4730880);
    k1_prep<<<dim3(4032), 256, 0, stream>>>(p);
    k2_gather<<<dim3(6216), 256, 0, stream>>>(p);
    k3_out<<<dim3(3744), 256, 0, stream>>>(p);
}

// Round 13
// 192.694 us; speedup vs baseline: 1.8589x; 1.1962x over previous
//
#include <hip/hip_runtime.h>

typedef __attribute__((ext_vector_type(8))) short short8;
typedef __attribute__((ext_vector_type(4))) float f32x4;

__device__ __forceinline__ float sigmoidf_(float x) { return 1.f / (1.f + __expf(-x)); }
__device__ __forceinline__ unsigned bf16rne(float x) {
    unsigned b = __float_as_uint(x);
    return (b + 0x7FFFu + ((b >> 16) & 1u)) >> 16;
}

// ws layout (float words):
//   OFFM:  lvl0 @0 (2359296), lvl1 @2359296 (589824), lvl2 @2949120 (147456)
//   MOD:   lvl0 @3096576 (1179648), lvl1 @4276224 (294912), lvl2 @4571136 (73728)
//   MEAN:  lvl0 @4644864 (65536), lvl1 @4710400 (16384), lvl2 @4726784 (4096)
//   WREP:  @4730880, 3*62784 floats; per lvl as u32:
//          [0..18432) WB dgemm B-frags | [36864..41472) WBO | [41472..55296) WBM
//   XTb:   @4919232 as u32 (bf16 pairs, 8 u32/px): lvl0 +0 (1048576),
//          lvl1 +1048576 (262144), lvl2 +1310720 (65536)
// S is GONE (fused into K2's LDS). d_out holds only final outputs now.

struct P {
    const float *sou0, *sou1, *sou2;
    const float *ref0, *ref1, *ref2;
    const float *ob0, *ob1, *ob2;
    const float *mb0, *mb1, *mb2;
    float* out;
    float* ws;
};

union U {
    uint4 u4; int4 i4; short8 s8; f32x4 f4;
};

// ---------------- K0: fused weight repack (all levels) --------------------------------
__global__ __launch_bounds__(256) void repack_all(
    const float* __restrict__ ow0, const float* __restrict__ mw0, const float* __restrict__ rw0,
    const float* __restrict__ ow1, const float* __restrict__ mw1, const float* __restrict__ rw1,
    const float* __restrict__ ow2, const float* __restrict__ mw2, const float* __restrict__ rw2,
    float* __restrict__ dst) {
    const int lvl = blockIdx.y;
    const float* ow = lvl == 0 ? ow0 : (lvl == 1 ? ow1 : ow2);
    const float* mw = lvl == 0 ? mw0 : (lvl == 1 ? mw1 : mw2);
    const float* rw = lvl == 0 ? rw0 : (lvl == 1 ? rw1 : rw2);
    unsigned* d = (unsigned*)(dst + lvl * 62784);
    int i = blockIdx.x * 256 + threadIdx.x;
    if (i < 18432) {  // WB (dgemm): ((wvu*18+ks)*64+lane)*4+jw
        int jw = i & 3;
        int lane = (i >> 2) & 63;
        int t3 = i >> 8;
        int ks = t3 % 18, wvu = t3 / 18;
        int o = wvu * 16 + (lane & 15);
        int c0 = ks * 32 + (lane >> 4) * 8 + 2 * jw;
        int g0 = c0 / 144, r0 = c0 % 144;
        int c1 = c0 + 1;
        int g1 = c1 / 144, r1 = c1 % 144;
        float w0 = rw[o * 576 + (g0 * 16 + (r0 & 15)) * 9 + (r0 >> 4)];
        float w1 = rw[o * 576 + (g1 * 16 + (r1 & 15)) * 9 + (r1 >> 4)];
        d[i] = bf16rne(w0) | (bf16rne(w1) << 16);
    } else if (i < 23040) {  // WBO
        int o2 = i - 18432;
        int jw = o2 & 3;
        int lane = (o2 >> 2) & 63;
        int t2 = o2 >> 8;
        int tap = t2 >> 1, nt = t2 & 1;
        int n = nt * 16 + (lane & 15);
        int ic0 = (lane >> 4) * 8 + 2 * jw;
        float w0 = (n < 18) ? ow[n * 288 + ic0 * 9 + tap] : 0.f;
        float w1 = (n < 18) ? ow[n * 288 + (ic0 + 1) * 9 + tap] : 0.f;
        d[36864 + o2] = bf16rne(w0) | (bf16rne(w1) << 16);
    } else if (i < 36864) {  // WBM
        int o3 = i - 23040;
        int jw = o3 & 3;
        int lane = (o3 >> 2) & 63;
        int t3 = o3 >> 8;
        int nt = t3 % 3, tc = t3 / 3;
        int tap = tc >> 1, c = tc & 1;
        int n = nt * 16 + (lane & 15);
        int ic0 = c * 32 + (lane >> 4) * 8 + 2 * jw;
        float w0 = (n < 36) ? mw[n * 576 + ic0 * 9 + tap] : 0.f;
        float w1 = (n < 36) ? mw[n * 576 + (ic0 + 1) * 9 + tap] : 0.f;
        d[41472 + o3] = bf16rne(w0) | (bf16rne(w1) << 16);
    }
}

// ---------------- K1: MFMA offset_conv(2688) + MFMA mod_conv(672) + transpose(672) ----
__global__ __launch_bounds__(256) void k1_prep(P p) {
    __shared__ __align__(16) char smem[28512];
    const int t = blockIdx.x;
    float* ws = p.ws;
    const int tid = threadIdx.x;

    if (t < 2688) {  // ---- offset conv GEMM
        int lvl, j;
        if (t < 2048) { lvl = 0; j = t; }
        else if (t < 2560) { lvl = 1; j = t - 2048; }
        else { lvl = 2; j = t - 2560; }
        const int logW = 7 - lvl;
        const int W = 1 << logW, H = W, HW = H * W;
        const int nper = 256 >> (2 * lvl);
        const int qb = j % nper, g = (j / nper) & 3, b = j / (nper * 4);
        const int q0 = qb * 64;
        const int hlo = q0 >> logW;
        const int xlo = q0 & (W - 1);
        const int cols = (W >= 64) ? 66 : 34;
        const int rcTot = (W >= 64) ? 198 : 136;
        const float* sou = lvl == 0 ? p.sou0 : (lvl == 1 ? p.sou1 : p.sou2);
        const float* ref = lvl == 0 ? p.ref0 : (lvl == 1 ? p.ref1 : p.ref2);
        const float* bases = sou + (size_t)(b * 64 + g * 16) * HW;
        const float* baser = ref + (size_t)(b * 64 + g * 16) * HW;
        unsigned* ldsW = (unsigned*)smem;
        const bool sact = tid < rcTot;
        const int srow = tid / cols, scol = tid - srow * cols;
        const int grow = hlo - 1 + srow, gcol = xlo - 1 + scol;
        const bool inb = sact && grow >= 0 && grow < H && gcol >= 0 && gcol < W;
        const size_t goff = inb ? ((size_t)grow * W + gcol) : 0;
#pragma unroll
        for (int ic = 0; ic < 32; ic += 2) {
            float v0 = 0.f, v1 = 0.f;
            if (inb) {
                const float* p0 = (ic < 16) ? bases + (size_t)ic * HW
                                            : baser + (size_t)(ic - 16) * HW;
                v0 = p0[goff]; v1 = p0[HW + goff];
            }
            if (sact) ldsW[tid * 20 + (ic >> 1)] = bf16rne(v0) | (bf16rne(v1) << 16);
        }
        __syncthreads();
        const int wvu = __builtin_amdgcn_readfirstlane(tid >> 6);
        const int lane = tid & 63, quad = lane >> 4, lo16 = lane & 15;
        const int qg = q0 + wvu * 16 + lo16;
        const int rowB = (qg >> logW) - hlo;
        const int colB = (qg & (W - 1)) - xlo;
        const unsigned short* ldsS = (const unsigned short*)smem;
        const unsigned* WBO = (const unsigned*)(ws + 4730880 + lvl * 62784) + 36864;
        f32x4 acc[2];
        acc[0] = (f32x4){0.f, 0.f, 0.f, 0.f};
        acc[1] = (f32x4){0.f, 0.f, 0.f, 0.f};
#pragma unroll
        for (int tap = 0; tap < 9; ++tap) {
            const int ky = tap / 3, kx = tap - ky * 3;
            const int rc = (rowB + ky) * cols + colB + kx;
            U au; au.s8 = *(const short8*)&ldsS[rc * 40 + quad * 8];
#pragma unroll
            for (int nt = 0; nt < 2; ++nt) {
                U bu; bu.u4 = *(const uint4*)(WBO + ((tap * 2 + nt) * 64 + lane) * 4);
                acc[nt] = __builtin_amdgcn_mfma_f32_16x16x32_bf16(au.s8, bu.s8, acc[nt], 0, 0, 0);
            }
        }
        const float* bias = lvl == 0 ? p.ob0 : (lvl == 1 ? p.ob1 : p.ob2);
        float* OFFM = ws + (lvl == 0 ? 0 : (lvl == 1 ? 2359296 : 2949120));
        const float rng = 0.25f * (float)H;
#pragma unroll
        for (int nt = 0; nt < 2; ++nt) {
            const int o = nt * 16 + lo16;
            if (o < 18) {
                const float bb = bias[o];
                float* op = OFFM + (size_t)(b * 72 + g * 18 + o) * HW + q0 + wvu * 16 + quad * 4;
#pragma unroll
                for (int rg = 0; rg < 4; ++rg)
                    op[rg] = rng * (2.f * sigmoidf_(acc[nt][rg] + bb) - 1.f);
            }
        }
    } else if (t < 3360) {  // ---- mod conv GEMM
        const int i1 = t - 2688;
        int lvl, j;
        if (i1 < 512) { lvl = 0; j = i1; }
        else if (i1 < 640) { lvl = 1; j = i1 - 512; }
        else { lvl = 2; j = i1 - 640; }
        const int logW = 7 - lvl;
        const int W = 1 << logW, H = W, HW = H * W;
        const int nper = 256 >> (2 * lvl);
        const int qb = j % nper, b = j / nper;
        const int q0 = qb * 64;
        const int hlo = q0 >> logW;
        const int xlo = q0 & (W - 1);
        const int cols = (W >= 64) ? 66 : 34;
        const int rcTot = (W >= 64) ? 198 : 136;
        const float* sou = lvl == 0 ? p.sou0 : (lvl == 1 ? p.sou1 : p.sou2);
        const float* base = sou + (size_t)b * 64 * HW;
        unsigned* ldsW = (unsigned*)smem;
        const bool sact = tid < rcTot;
        const int srow = tid / cols, scol = tid - srow * cols;
        const int grow = hlo - 1 + srow, gcol = xlo - 1 + scol;
        const bool inb = sact && grow >= 0 && grow < H && gcol >= 0 && gcol < W;
        const size_t goff = inb ? ((size_t)grow * W + gcol) : 0;
#pragma unroll
        for (int ic = 0; ic < 64; ic += 2) {
            float v0 = 0.f, v1 = 0.f;
            if (inb) {
                const float* p0 = base + (size_t)ic * HW;
                v0 = p0[goff]; v1 = p0[HW + goff];
            }
            if (sact) ldsW[tid * 36 + (ic >> 1)] = bf16rne(v0) | (bf16rne(v1) << 16);
        }
        __syncthreads();
        const int wvu = __builtin_amdgcn_readfirstlane(tid >> 6);
        const int lane = tid & 63, quad = lane >> 4, lo16 = lane & 15;
        const int qg = q0 + wvu * 16 + lo16;
        const int rowB = (qg >> logW) - hlo;
        const int colB = (qg & (W - 1)) - xlo;
        const unsigned short* ldsS = (const unsigned short*)smem;
        const unsigned* WBM = (const unsigned*)(ws + 4730880 + lvl * 62784) + 41472;
        f32x4 acc[3];
        acc[0] = (f32x4){0.f, 0.f, 0.f, 0.f};
        acc[1] = (f32x4){0.f, 0.f, 0.f, 0.f};
        acc[2] = (f32x4){0.f, 0.f, 0.f, 0.f};
#pragma unroll
        for (int tap = 0; tap < 9; ++tap) {
            const int ky = tap / 3, kx = tap - ky * 3;
            const int rc = (rowB + ky) * cols + colB + kx;
#pragma unroll
            for (int c = 0; c < 2; ++c) {
                U au; au.s8 = *(const short8*)&ldsS[rc * 72 + c * 32 + quad * 8];
#pragma unroll
                for (int nt = 0; nt < 3; ++nt) {
                    U bu;
                    bu.u4 = *(const uint4*)(WBM + (((tap * 2 + c) * 3 + nt) * 64 + lane) * 4);
                    acc[nt] = __builtin_amdgcn_mfma_f32_16x16x32_bf16(au.s8, bu.s8, acc[nt], 0, 0, 0);
                }
            }
        }
        const float* bias = lvl == 0 ? p.mb0 : (lvl == 1 ? p.mb1 : p.mb2);
        float* MOD = ws + (lvl == 0 ? 3096576 : (lvl == 1 ? 4276224 : 4571136));
#pragma unroll
        for (int nt = 0; nt < 3; ++nt) {
            const int o = nt * 16 + lo16;
            if (o < 36) {
                const float bb = bias[o];
                float* op = MOD + (size_t)(b * 36 + o) * HW + q0 + wvu * 16 + quad * 4;
#pragma unroll
                for (int rg = 0; rg < 4; ++rg)
                    op[rg] = 2.f * sigmoidf_(acc[nt][rg] + bb);
            }
        }
    } else {  // ---- transpose (b,64,H,W) -> XTb bf16 pairs (b,g,HW,16)
        const int i2 = t - 3360;
        int lvl, j;
        if (i2 < 512) { lvl = 0; j = i2; }
        else if (i2 < 640) { lvl = 1; j = i2 - 512; }
        else { lvl = 2; j = i2 - 640; }
        const int HW = 16384 >> (2 * lvl);
        const int nper = 64 >> (2 * lvl);
        const int qb = j % nper, g = (j / nper) & 3, b = j / (nper * 4);
        const float* sou = lvl == 0 ? p.sou0 : (lvl == 1 ? p.sou1 : p.sou2);
        unsigned* XTb = (unsigned*)(ws + 4919232) +
                        (lvl == 0 ? 0 : (lvl == 1 ? 1048576 : 1310720));
        float (*tile)[17] = (float(*)[17])smem;
        const int q0 = qb * 256;
        const float* src = sou + (size_t)(b * 64 + g * 16) * HW + q0;
#pragma unroll
        for (int c = 0; c < 16; ++c) tile[tid][c] = src[(size_t)c * HW + tid];
        __syncthreads();
        uint4* dst = (uint4*)(XTb + ((size_t)(b * 4 + g) * HW + q0) * 8);
#pragma unroll
        for (int u = 0; u < 2; ++u) {
            int f4 = u * 256 + tid;
            int px = f4 >> 1, hf = (f4 & 1) * 8;
            uint4 w;
            w.x = bf16rne(tile[px][hf + 0]) | (bf16rne(tile[px][hf + 1]) << 16);
            w.y = bf16rne(tile[px][hf + 2]) | (bf16rne(tile[px][hf + 3]) << 16);
            w.z = bf16rne(tile[px][hf + 4]) | (bf16rne(tile[px][hf + 5]) << 16);
            w.w = bf16rne(tile[px][hf + 6]) | (bf16rne(tile[px][hf + 7]) << 16);
            dst[f4] = w;
        }
    }
}

// ---------------- K2: FUSED gather+dgemm(672) + mean(168) -----------------------------
// Per 64-px block: 3 chunks of 12 gk; phase A gathers the S-chunk (bf16 XT, 2 uint4
// per corner) straight into LDS (24 KB), phase B runs 6 MFMA k-steps on it. S never
// touches HBM (R12: 48.7 MB S-write + ~50 MB S-read eliminated).
__global__ __launch_bounds__(256) void k2_fused(P p) {
    __shared__ unsigned lds[96 * 64];  // 24 KB
    const int t = blockIdx.x;
    float* ws = p.ws;
    const int tid = threadIdx.x;
    if (t < 672) {
        int lvl, j;
        if (t < 512) { lvl = 0; j = t; }
        else if (t < 640) { lvl = 1; j = t - 512; }
        else { lvl = 2; j = t - 640; }
        const int logW = 7 - lvl;
        const int W = 1 << logW, H = W, HW = H * W;
        const int nper = 256 >> (2 * lvl);
        const int qb = j % nper, b = j / nper;
        const int q0 = qb * 64;
        const float* OFFM = ws + (lvl == 0 ? 0 : (lvl == 1 ? 2359296 : 2949120));
        const float* MOD = ws + (lvl == 0 ? 3096576 : (lvl == 1 ? 4276224 : 4571136));
        const unsigned* XTb = (const unsigned*)(ws + 4919232) +
                              (lvl == 0 ? 0 : (lvl == 1 ? 1048576 : 1310720));
        const unsigned* WB = (const unsigned*)(ws + 4730880 + lvl * 62784);
        float* outp = p.out + (lvl == 0 ? 655360 : (lvl == 1 ? 131072 : 0));
        const int wvu = __builtin_amdgcn_readfirstlane(tid >> 6);
        const int lane = tid & 63, quad = lane >> 4, lo16 = lane & 15;
        f32x4 acc[4];
#pragma unroll
        for (int mt = 0; mt < 4; ++mt) acc[mt] = (f32x4){0.f, 0.f, 0.f, 0.f};
        for (int c = 0; c < 3; ++c) {
            if (c) __syncthreads();
            // ---- phase A: gather 12 gk x 64 px into LDS
#pragma unroll
            for (int it = 0; it < 3; ++it) {
                const int task = it * 256 + tid;
                const int gkl = task >> 6, px = task & 63;
                const int gk = c * 12 + gkl;
                const int g = gk / 9, k = gk - g * 9;
                const int q = q0 + px;
                const int h = q >> logW, xp = q & (W - 1);
                const int ky = k / 3, kx = k - ky * 3;
                float dy = OFFM[(size_t)(b * 72 + g * 18 + 2 * k) * HW + q];
                float dx = OFFM[(size_t)(b * 72 + g * 18 + 2 * k + 1) * HW + q];
                float m = MOD[(size_t)(b * 36 + g * 9 + k) * HW + q];
                float py = (float)(h - 1 + ky) + dy;
                float pxx = (float)(xp - 1 + kx) + dx;
                float y0f = floorf(py), x0f = floorf(pxx);
                float wy = py - y0f, wx = pxx - x0f;
                int y0 = (int)y0f, x0 = (int)x0f;
                const unsigned* xg = XTb + (size_t)(b * 4 + g) * HW * 8;
                float s[16];
#pragma unroll
                for (int cc = 0; cc < 16; ++cc) s[cc] = 0.f;
#pragma unroll
                for (int cor = 0; cor < 4; ++cor) {
                    int yy = y0 + (cor >> 1), xx = x0 + (cor & 1);
                    float cw = ((cor >> 1) ? wy : 1.f - wy) * ((cor & 1) ? wx : 1.f - wx);
                    cw = (yy >= 0 && yy < H && xx >= 0 && xx < W) ? cw * m : 0.f;
                    int yc = min(max(yy, 0), H - 1), xc = min(max(xx, 0), W - 1);
                    const uint4* cp = (const uint4*)(xg + (size_t)((yc << logW) + xc) * 8);
                    unsigned cbuf[8];
                    *(uint4*)&cbuf[0] = cp[0];
                    *(uint4*)&cbuf[4] = cp[1];
#pragma unroll
                    for (int pr = 0; pr < 8; ++pr) {
                        float lo = __uint_as_float(cbuf[pr] << 16);
                        float hi = __uint_as_float(cbuf[pr] & 0xFFFF0000u);
                        s[2 * pr] = fmaf(cw, lo, s[2 * pr]);
                        s[2 * pr + 1] = fmaf(cw, hi, s[2 * pr + 1]);
                    }
                }
#pragma unroll
                for (int pr = 0; pr < 8; ++pr)
                    lds[(gkl * 8 + pr) * 64 + px] =
                        bf16rne(s[2 * pr]) | (bf16rne(s[2 * pr + 1]) << 16);
            }
            __syncthreads();
            // ---- phase B: 6 MFMA k-steps on the chunk
            uint4 bfr[6];
#pragma unroll
            for (int k6 = 0; k6 < 6; ++k6)
                bfr[k6] = *(const uint4*)(WB + (((wvu * 18 + c * 6 + k6) * 64 + lane) << 2));
#pragma unroll
            for (int k6 = 0; k6 < 6; ++k6) {
                const int rb = k6 * 16 + quad * 4;
                U bu; bu.u4 = bfr[k6];
#pragma unroll
                for (int mt = 0; mt < 4; ++mt) {
                    const int px = mt * 16 + lo16;
                    U au;
                    au.i4.x = (int)lds[(rb + 0) * 64 + px];
                    au.i4.y = (int)lds[(rb + 1) * 64 + px];
                    au.i4.z = (int)lds[(rb + 2) * 64 + px];
                    au.i4.w = (int)lds[(rb + 3) * 64 + px];
                    acc[mt] = __builtin_amdgcn_mfma_f32_16x16x32_bf16(au.s8, bu.s8, acc[mt], 0, 0, 0);
                }
            }
        }
        float* op = outp + (size_t)(b * 64 + wvu * 16 + lo16) * HW + q0;
#pragma unroll
        for (int mt = 0; mt < 4; ++mt)
#pragma unroll
            for (int rg = 0; rg < 4; ++rg)
                op[mt * 16 + quad * 4 + rg] = acc[mt][rg];
    } else {
        // ---- mean of dy/dx channels
        int i = t - 672;
        int lvl, j;
        if (i < 128) { lvl = 0; j = i; }
        else if (i < 160) { lvl = 1; j = i - 128; }
        else { lvl = 2; j = i - 160; }
        const int HW = 16384 >> (2 * lvl);
        const int nper = 64 >> (2 * lvl);
        const int qb = j % nper, b = j / nper;
        const float* OFFM = ws + (lvl == 0 ? 0 : (lvl == 1 ? 2359296 : 2949120));
        float* MEAN = ws + (lvl == 0 ? 4644864 : (lvl == 1 ? 4710400 : 4726784));
        const int q = qb * 256 + tid;
        const float* pp = OFFM + (size_t)b * 72 * HW + q;
        float sy = 0.f, sx = 0.f;
#pragma unroll
        for (int u = 0; u < 36; ++u) {
            sy += pp[(size_t)(2 * u) * HW];
            sx += pp[(size_t)(2 * u + 1) * HW];
        }
        MEAN[(size_t)(b * 2) * HW + q] = sy * (1.f / 36.f);
        MEAN[(size_t)(b * 2 + 1) * HW + q] = sx * (1.f / 36.f);
    }
}

// ---------------- K3: upsample only (3072) --------------------------------------------
__global__ __launch_bounds__(256) void k3_up(P p) {
    float* ws = p.ws;
    int flat = ((int)blockIdx.x * 256 + (int)threadIdx.x) * 4;
    int lvl = flat >> 20;
    int r = flat & 1048575;
    int b = r >> 19, c = (r >> 18) & 1;
    int pix = r & 262143;
    int yo = pix >> 9, xo = pix & 511;
    const int H = 128 >> lvl, W = H;
    const float* MEAN = ws + (lvl == 0 ? 4644864 : (lvl == 1 ? 4710400 : 4726784));
    const float* m = MEAN + (size_t)(b * 2 + c) * H * W;
    float* o = p.out + (lvl == 0 ? 4849664 : (lvl == 1 ? 3801088 : 2752512)) +
               ((size_t)(b * 2 + c) * 512 + yo) * 512 + xo;
    const float fs = (float)(4 << lvl);
    const float sc = (float)(H - 1) * (1.f / 511.f);
    float sy = yo * sc;
    int y0 = min((int)sy, H - 2);
    float wy = sy - (float)y0;
    float rr[4];
#pragma unroll
    for (int u = 0; u < 4; ++u) {
        float sx = (float)(xo + u) * sc;
        int x0 = min((int)sx, W - 2);
        float wx = sx - (float)x0;
        float v00 = m[y0 * W + x0], v01 = m[y0 * W + x0 + 1];
        float v10 = m[(y0 + 1) * W + x0], v11 = m[(y0 + 1) * W + x0 + 1];
        float r0 = v00 * (1.f - wy) + v10 * wy;
        float r1 = v01 * (1.f - wy) + v11 * wy;
        rr[u] = (r0 * (1.f - wx) + r1 * wx) * fs;
    }
    *(float4*)o = make_float4(rr[0], rr[1], rr[2], rr[3]);
}

extern "C" void kernel_launch(void* const* d_in, const int* in_sizes, int n_in,
                              void* d_out, int out_size, void* d_ws, size_t ws_size,
                              hipStream_t stream) {
    const float* fin[21];
    for (int i = 0; i < 21; ++i) fin[i] = (const float*)d_in[i];
    P p;
    if (in_sizes[1] == in_sizes[0]) {  // dict order sou1,ref1,sou2,ref2,sou3,ref3
        p.sou0 = fin[0]; p.ref0 = fin[1];
        p.sou1 = fin[2]; p.ref1 = fin[3];
        p.sou2 = fin[4]; p.ref2 = fin[5];
    } else {  // arg order
        p.sou0 = fin[0]; p.sou1 = fin[1]; p.sou2 = fin[2];
        p.ref0 = fin[3]; p.ref1 = fin[4]; p.ref2 = fin[5];
    }
    p.ob0 = fin[7]; p.mb0 = fin[9];
    p.ob1 = fin[12]; p.mb1 = fin[14];
    p.ob2 = fin[17]; p.mb2 = fin[19];
    p.out = (float*)d_out;
    p.ws = (float*)d_ws;

    repack_all<<<dim3(144, 3), 256, 0, stream>>>(
        fin[6], fin[8], fin[10], fin[11], fin[13], fin[15], fin[16], fin[18], fin[20],
        p.ws + 4730880);
    k1_prep<<<dim3(4032), 256, 0, stream>>>(p);
    k2_fused<<<dim3(840), 256, 0, stream>>>(p);
    k3_up<<<dim3(3072), 256, 0, stream>>>(p);
}

// Round 14
// 186.280 us; speedup vs baseline: 1.9229x; 1.0344x over previous
//
#include <hip/hip_runtime.h>

typedef __attribute__((ext_vector_type(8))) short short8;
typedef __attribute__((ext_vector_type(4))) float f32x4;

__device__ __forceinline__ float sigmoidf_(float x) { return 1.f / (1.f + __expf(-x)); }
__device__ __forceinline__ unsigned bf16rne(float x) {
    unsigned b = __float_as_uint(x);
    return (b + 0x7FFFu + ((b >> 16) & 1u)) >> 16;
}

// ws layout (float words):
//   OFFM:  lvl0 @0 (2359296), lvl1 @2359296 (589824), lvl2 @2949120 (147456)
//   MOD:   lvl0 @3096576 (1179648), lvl1 @4276224 (294912), lvl2 @4571136 (73728)
//   MEAN:  lvl0 @4644864 (65536), lvl1 @4710400 (16384), lvl2 @4726784 (4096)
//   WREP:  @4730880, 3*62784 floats; per lvl as u32:
//          [0..18432) WB dgemm B-frags | [36864..41472) WBO | [41472..55296) WBM
//   XTb:   @4919232 as u32 (bf16 pairs, 8 u32/px): lvl0 +0 (1048576),
//          lvl1 +1048576 (262144), lvl2 +1310720 (65536)

struct P {
    const float *sou0, *sou1, *sou2;
    const float *ref0, *ref1, *ref2;
    const float *ob0, *ob1, *ob2;
    const float *mb0, *mb1, *mb2;
    float* out;
    float* ws;
};

union U {
    uint4 u4; int4 i4; short8 s8; f32x4 f4;
};

// ---------------- K0: fused weight repack (all levels) --------------------------------
__global__ __launch_bounds__(256) void repack_all(
    const float* __restrict__ ow0, const float* __restrict__ mw0, const float* __restrict__ rw0,
    const float* __restrict__ ow1, const float* __restrict__ mw1, const float* __restrict__ rw1,
    const float* __restrict__ ow2, const float* __restrict__ mw2, const float* __restrict__ rw2,
    float* __restrict__ dst) {
    const int lvl = blockIdx.y;
    const float* ow = lvl == 0 ? ow0 : (lvl == 1 ? ow1 : ow2);
    const float* mw = lvl == 0 ? mw0 : (lvl == 1 ? mw1 : mw2);
    const float* rw = lvl == 0 ? rw0 : (lvl == 1 ? rw1 : rw2);
    unsigned* d = (unsigned*)(dst + lvl * 62784);
    int i = blockIdx.x * 256 + threadIdx.x;
    if (i < 18432) {  // WB (dgemm): ((wvu*18+ks)*64+lane)*4+jw
        int jw = i & 3;
        int lane = (i >> 2) & 63;
        int t3 = i >> 8;
        int ks = t3 % 18, wvu = t3 / 18;
        int o = wvu * 16 + (lane & 15);
        int c0 = ks * 32 + (lane >> 4) * 8 + 2 * jw;
        int g0 = c0 / 144, r0 = c0 % 144;
        int c1 = c0 + 1;
        int g1 = c1 / 144, r1 = c1 % 144;
        float w0 = rw[o * 576 + (g0 * 16 + (r0 & 15)) * 9 + (r0 >> 4)];
        float w1 = rw[o * 576 + (g1 * 16 + (r1 & 15)) * 9 + (r1 >> 4)];
        d[i] = bf16rne(w0) | (bf16rne(w1) << 16);
    } else if (i < 23040) {  // WBO
        int o2 = i - 18432;
        int jw = o2 & 3;
        int lane = (o2 >> 2) & 63;
        int t2 = o2 >> 8;
        int tap = t2 >> 1, nt = t2 & 1;
        int n = nt * 16 + (lane & 15);
        int ic0 = (lane >> 4) * 8 + 2 * jw;
        float w0 = (n < 18) ? ow[n * 288 + ic0 * 9 + tap] : 0.f;
        float w1 = (n < 18) ? ow[n * 288 + (ic0 + 1) * 9 + tap] : 0.f;
        d[36864 + o2] = bf16rne(w0) | (bf16rne(w1) << 16);
    } else if (i < 36864) {  // WBM
        int o3 = i - 23040;
        int jw = o3 & 3;
        int lane = (o3 >> 2) & 63;
        int t3 = o3 >> 8;
        int nt = t3 % 3, tc = t3 / 3;
        int tap = tc >> 1, c = tc & 1;
        int n = nt * 16 + (lane & 15);
        int ic0 = c * 32 + (lane >> 4) * 8 + 2 * jw;
        float w0 = (n < 36) ? mw[n * 576 + ic0 * 9 + tap] : 0.f;
        float w1 = (n < 36) ? mw[n * 576 + (ic0 + 1) * 9 + tap] : 0.f;
        d[41472 + o3] = bf16rne(w0) | (bf16rne(w1) << 16);
    }
}

// ---------------- K1: MFMA offset_conv(2688) + MFMA mod_conv(672) + transpose(672) ----
// Staging writes are b128 (8 ch per uint4): row stride 20/36 dw means 8 consecutive
// lanes cover all 32 banks -> conflict-free (R13's per-dword writes were 8-way
// conflicted: SQ_LDS_BANK_CONFLICT 1.81M).
__global__ __launch_bounds__(256) void k1_prep(P p) {
    __shared__ __align__(16) char smem[28512];
    const int t = blockIdx.x;
    float* ws = p.ws;
    const int tid = threadIdx.x;

    if (t < 2688) {  // ---- offset conv GEMM: 32ch -> 18(pad32), K=288
        int lvl, j;
        if (t < 2048) { lvl = 0; j = t; }
        else if (t < 2560) { lvl = 1; j = t - 2048; }
        else { lvl = 2; j = t - 2560; }
        const int logW = 7 - lvl;
        const int W = 1 << logW, H = W, HW = H * W;
        const int nper = 256 >> (2 * lvl);
        const int qb = j % nper, g = (j / nper) & 3, b = j / (nper * 4);
        const int q0 = qb * 64;
        const int hlo = q0 >> logW;
        const int xlo = q0 & (W - 1);
        const int cols = (W >= 64) ? 66 : 34;
        const int rcTot = (W >= 64) ? 198 : 136;
        const float* sou = lvl == 0 ? p.sou0 : (lvl == 1 ? p.sou1 : p.sou2);
        const float* ref = lvl == 0 ? p.ref0 : (lvl == 1 ? p.ref1 : p.ref2);
        const float* bases = sou + (size_t)(b * 64 + g * 16) * HW;
        const float* baser = ref + (size_t)(b * 64 + g * 16) * HW;
        unsigned* ldsW = (unsigned*)smem;  // row stride 20 dw (40 shorts)
        const bool sact = tid < rcTot;
        const int srow = tid / cols, scol = tid - srow * cols;
        const int grow = hlo - 1 + srow, gcol = xlo - 1 + scol;
        const bool inb = sact && grow >= 0 && grow < H && gcol >= 0 && gcol < W;
        const size_t goff = inb ? ((size_t)grow * W + gcol) : 0;
#pragma unroll
        for (int c8 = 0; c8 < 4; ++c8) {
            const float* p0 = (c8 < 2) ? bases + (size_t)(c8 * 8) * HW
                                       : baser + (size_t)((c8 - 2) * 8) * HW;
            float v[8];
#pragma unroll
            for (int jj = 0; jj < 8; ++jj) v[jj] = inb ? p0[(size_t)jj * HW + goff] : 0.f;
            if (sact) {
                uint4 wv;
                wv.x = bf16rne(v[0]) | (bf16rne(v[1]) << 16);
                wv.y = bf16rne(v[2]) | (bf16rne(v[3]) << 16);
                wv.z = bf16rne(v[4]) | (bf16rne(v[5]) << 16);
                wv.w = bf16rne(v[6]) | (bf16rne(v[7]) << 16);
                *(uint4*)&ldsW[tid * 20 + c8 * 4] = wv;
            }
        }
        __syncthreads();
        const int wvu = __builtin_amdgcn_readfirstlane(tid >> 6);
        const int lane = tid & 63, quad = lane >> 4, lo16 = lane & 15;
        const int qg = q0 + wvu * 16 + lo16;
        const int rowB = (qg >> logW) - hlo;
        const int colB = (qg & (W - 1)) - xlo;
        const unsigned short* ldsS = (const unsigned short*)smem;
        const unsigned* WBO = (const unsigned*)(ws + 4730880 + lvl * 62784) + 36864;
        f32x4 acc[2];
        acc[0] = (f32x4){0.f, 0.f, 0.f, 0.f};
        acc[1] = (f32x4){0.f, 0.f, 0.f, 0.f};
#pragma unroll
        for (int tap = 0; tap < 9; ++tap) {
            const int ky = tap / 3, kx = tap - ky * 3;
            const int rc = (rowB + ky) * cols + colB + kx;
            U au; au.s8 = *(const short8*)&ldsS[rc * 40 + quad * 8];
#pragma unroll
            for (int nt = 0; nt < 2; ++nt) {
                U bu; bu.u4 = *(const uint4*)(WBO + ((tap * 2 + nt) * 64 + lane) * 4);
                acc[nt] = __builtin_amdgcn_mfma_f32_16x16x32_bf16(au.s8, bu.s8, acc[nt], 0, 0, 0);
            }
        }
        const float* bias = lvl == 0 ? p.ob0 : (lvl == 1 ? p.ob1 : p.ob2);
        float* OFFM = ws + (lvl == 0 ? 0 : (lvl == 1 ? 2359296 : 2949120));
        const float rng = 0.25f * (float)H;
#pragma unroll
        for (int nt = 0; nt < 2; ++nt) {
            const int o = nt * 16 + lo16;
            if (o < 18) {
                const float bb = bias[o];
                float* op = OFFM + (size_t)(b * 72 + g * 18 + o) * HW + q0 + wvu * 16 + quad * 4;
#pragma unroll
                for (int rg = 0; rg < 4; ++rg)
                    op[rg] = rng * (2.f * sigmoidf_(acc[nt][rg] + bb) - 1.f);
            }
        }
    } else if (t < 3360) {  // ---- mod conv GEMM: 64ch -> 36(pad48), K=576
        const int i1 = t - 2688;
        int lvl, j;
        if (i1 < 512) { lvl = 0; j = i1; }
        else if (i1 < 640) { lvl = 1; j = i1 - 512; }
        else { lvl = 2; j = i1 - 640; }
        const int logW = 7 - lvl;
        const int W = 1 << logW, H = W, HW = H * W;
        const int nper = 256 >> (2 * lvl);
        const int qb = j % nper, b = j / nper;
        const int q0 = qb * 64;
        const int hlo = q0 >> logW;
        const int xlo = q0 & (W - 1);
        const int cols = (W >= 64) ? 66 : 34;
        const int rcTot = (W >= 64) ? 198 : 136;
        const float* sou = lvl == 0 ? p.sou0 : (lvl == 1 ? p.sou1 : p.sou2);
        const float* base = sou + (size_t)b * 64 * HW;
        unsigned* ldsW = (unsigned*)smem;  // row stride 36 dw (72 shorts)
        const bool sact = tid < rcTot;
        const int srow = tid / cols, scol = tid - srow * cols;
        const int grow = hlo - 1 + srow, gcol = xlo - 1 + scol;
        const bool inb = sact && grow >= 0 && grow < H && gcol >= 0 && gcol < W;
        const size_t goff = inb ? ((size_t)grow * W + gcol) : 0;
#pragma unroll
        for (int c8 = 0; c8 < 8; ++c8) {
            const float* p0 = base + (size_t)(c8 * 8) * HW;
            float v[8];
#pragma unroll
            for (int jj = 0; jj < 8; ++jj) v[jj] = inb ? p0[(size_t)jj * HW + goff] : 0.f;
            if (sact) {
                uint4 wv;
                wv.x = bf16rne(v[0]) | (bf16rne(v[1]) << 16);
                wv.y = bf16rne(v[2]) | (bf16rne(v[3]) << 16);
                wv.z = bf16rne(v[4]) | (bf16rne(v[5]) << 16);
                wv.w = bf16rne(v[6]) | (bf16rne(v[7]) << 16);
                *(uint4*)&ldsW[tid * 36 + c8 * 4] = wv;
            }
        }
        __syncthreads();
        const int wvu = __builtin_amdgcn_readfirstlane(tid >> 6);
        const int lane = tid & 63, quad = lane >> 4, lo16 = lane & 15;
        const int qg = q0 + wvu * 16 + lo16;
        const int rowB = (qg >> logW) - hlo;
        const int colB = (qg & (W - 1)) - xlo;
        const unsigned short* ldsS = (const unsigned short*)smem;
        const unsigned* WBM = (const unsigned*)(ws + 4730880 + lvl * 62784) + 41472;
        f32x4 acc[3];
        acc[0] = (f32x4){0.f, 0.f, 0.f, 0.f};
        acc[1] = (f32x4){0.f, 0.f, 0.f, 0.f};
        acc[2] = (f32x4){0.f, 0.f, 0.f, 0.f};
#pragma unroll
        for (int tap = 0; tap < 9; ++tap) {
            const int ky = tap / 3, kx = tap - ky * 3;
            const int rc = (rowB + ky) * cols + colB + kx;
#pragma unroll
            for (int c = 0; c < 2; ++c) {
                U au; au.s8 = *(const short8*)&ldsS[rc * 72 + c * 32 + quad * 8];
#pragma unroll
                for (int nt = 0; nt < 3; ++nt) {
                    U bu;
                    bu.u4 = *(const uint4*)(WBM + (((tap * 2 + c) * 3 + nt) * 64 + lane) * 4);
                    acc[nt] = __builtin_amdgcn_mfma_f32_16x16x32_bf16(au.s8, bu.s8, acc[nt], 0, 0, 0);
                }
            }
        }
        const float* bias = lvl == 0 ? p.mb0 : (lvl == 1 ? p.mb1 : p.mb2);
        float* MOD = ws + (lvl == 0 ? 3096576 : (lvl == 1 ? 4276224 : 4571136));
#pragma unroll
        for (int nt = 0; nt < 3; ++nt) {
            const int o = nt * 16 + lo16;
            if (o < 36) {
                const float bb = bias[o];
                float* op = MOD + (size_t)(b * 36 + o) * HW + q0 + wvu * 16 + quad * 4;
#pragma unroll
                for (int rg = 0; rg < 4; ++rg)
                    op[rg] = 2.f * sigmoidf_(acc[nt][rg] + bb);
            }
        }
    } else {  // ---- transpose (b,64,H,W) -> XTb bf16 pairs (b,g,HW,16)
        const int i2 = t - 3360;
        int lvl, j;
        if (i2 < 512) { lvl = 0; j = i2; }
        else if (i2 < 640) { lvl = 1; j = i2 - 512; }
        else { lvl = 2; j = i2 - 640; }
        const int HW = 16384 >> (2 * lvl);
        const int nper = 64 >> (2 * lvl);
        const int qb = j % nper, g = (j / nper) & 3, b = j / (nper * 4);
        const float* sou = lvl == 0 ? p.sou0 : (lvl == 1 ? p.sou1 : p.sou2);
        unsigned* XTb = (unsigned*)(ws + 4919232) +
                        (lvl == 0 ? 0 : (lvl == 1 ? 1048576 : 1310720));
        float (*tile)[17] = (float(*)[17])smem;
        const int q0 = qb * 256;
        const float* src = sou + (size_t)(b * 64 + g * 16) * HW + q0;
#pragma unroll
        for (int c = 0; c < 16; ++c) tile[tid][c] = src[(size_t)c * HW + tid];
        __syncthreads();
        uint4* dst = (uint4*)(XTb + ((size_t)(b * 4 + g) * HW + q0) * 8);
#pragma unroll
        for (int u = 0; u < 2; ++u) {
            int f4 = u * 256 + tid;
            int px = f4 >> 1, hf = (f4 & 1) * 8;
            uint4 w;
            w.x = bf16rne(tile[px][hf + 0]) | (bf16rne(tile[px][hf + 1]) << 16);
            w.y = bf16rne(tile[px][hf + 2]) | (bf16rne(tile[px][hf + 3]) << 16);
            w.z = bf16rne(tile[px][hf + 4]) | (bf16rne(tile[px][hf + 5]) << 16);
            w.w = bf16rne(tile[px][hf + 6]) | (bf16rne(tile[px][hf + 7]) << 16);
            dst[f4] = w;
        }
    }
}

// ---------------- K2: FUSED gather+dgemm(1344, 32-px tiles) + mean(168) ---------------
// 32-px tiles double blocks to 1344 (5.25/CU vs R13's 2.6). LDS rows padded to 33 dw:
// phase-A writes and quad-offset A-reads spread over all banks (<=2-way = free).
__global__ __launch_bounds__(256) void k2_fused(P p) {
    __shared__ unsigned lds[96 * 33];  // 12.7 KB
    const int t = blockIdx.x;
    float* ws = p.ws;
    const int tid = threadIdx.x;
    if (t < 1344) {
        int lvl, j;
        if (t < 1024) { lvl = 0; j = t; }
        else if (t < 1280) { lvl = 1; j = t - 1024; }
        else { lvl = 2; j = t - 1280; }
        const int logW = 7 - lvl;
        const int W = 1 << logW, H = W, HW = H * W;
        const int nper = 512 >> (2 * lvl);
        const int qb = j % nper, b = j / nper;
        const int q0 = qb * 32;
        const float* OFFM = ws + (lvl == 0 ? 0 : (lvl == 1 ? 2359296 : 2949120));
        const float* MOD = ws + (lvl == 0 ? 3096576 : (lvl == 1 ? 4276224 : 4571136));
        const unsigned* XTb = (const unsigned*)(ws + 4919232) +
                              (lvl == 0 ? 0 : (lvl == 1 ? 1048576 : 1310720));
        const unsigned* WB = (const unsigned*)(ws + 4730880 + lvl * 62784);
        float* outp = p.out + (lvl == 0 ? 655360 : (lvl == 1 ? 131072 : 0));
        const int wvu = __builtin_amdgcn_readfirstlane(tid >> 6);
        const int lane = tid & 63, quad = lane >> 4, lo16 = lane & 15;
        f32x4 acc[2];
        acc[0] = (f32x4){0.f, 0.f, 0.f, 0.f};
        acc[1] = (f32x4){0.f, 0.f, 0.f, 0.f};
        for (int c = 0; c < 3; ++c) {
            if (c) __syncthreads();
            // ---- phase A: gather 12 gk x 32 px into LDS (384 tasks)
#pragma unroll
            for (int it = 0; it < 2; ++it) {
                const int task = it * 256 + tid;
                if (task < 384) {
                    const int gkl = task >> 5, px = task & 31;
                    const int gk = c * 12 + gkl;
                    const int g = gk / 9, k = gk - g * 9;
                    const int q = q0 + px;
                    const int h = q >> logW, xp = q & (W - 1);
                    const int ky = k / 3, kx = k - ky * 3;
                    float dy = OFFM[(size_t)(b * 72 + g * 18 + 2 * k) * HW + q];
                    float dx = OFFM[(size_t)(b * 72 + g * 18 + 2 * k + 1) * HW + q];
                    float m = MOD[(size_t)(b * 36 + g * 9 + k) * HW + q];
                    float py = (float)(h - 1 + ky) + dy;
                    float pxx = (float)(xp - 1 + kx) + dx;
                    float y0f = floorf(py), x0f = floorf(pxx);
                    float wy = py - y0f, wx = pxx - x0f;
                    int y0 = (int)y0f, x0 = (int)x0f;
                    const unsigned* xg = XTb + (size_t)(b * 4 + g) * HW * 8;
                    float s[16];
#pragma unroll
                    for (int cc = 0; cc < 16; ++cc) s[cc] = 0.f;
#pragma unroll
                    for (int cor = 0; cor < 4; ++cor) {
                        int yy = y0 + (cor >> 1), xx = x0 + (cor & 1);
                        float cw = ((cor >> 1) ? wy : 1.f - wy) * ((cor & 1) ? wx : 1.f - wx);
                        cw = (yy >= 0 && yy < H && xx >= 0 && xx < W) ? cw * m : 0.f;
                        int yc = min(max(yy, 0), H - 1), xc = min(max(xx, 0), W - 1);
                        const uint4* cp = (const uint4*)(xg + (size_t)((yc << logW) + xc) * 8);
                        unsigned cbuf[8];
                        *(uint4*)&cbuf[0] = cp[0];
                        *(uint4*)&cbuf[4] = cp[1];
#pragma unroll
                        for (int pr = 0; pr < 8; ++pr) {
                            float lo = __uint_as_float(cbuf[pr] << 16);
                            float hi = __uint_as_float(cbuf[pr] & 0xFFFF0000u);
                            s[2 * pr] = fmaf(cw, lo, s[2 * pr]);
                            s[2 * pr + 1] = fmaf(cw, hi, s[2 * pr + 1]);
                        }
                    }
#pragma unroll
                    for (int pr = 0; pr < 8; ++pr)
                        lds[(gkl * 8 + pr) * 33 + px] =
                            bf16rne(s[2 * pr]) | (bf16rne(s[2 * pr + 1]) << 16);
                }
            }
            __syncthreads();
            // ---- phase B: 6 MFMA k-steps, 2 m-tiles
            uint4 bfr[6];
#pragma unroll
            for (int k6 = 0; k6 < 6; ++k6)
                bfr[k6] = *(const uint4*)(WB + (((wvu * 18 + c * 6 + k6) * 64 + lane) << 2));
#pragma unroll
            for (int k6 = 0; k6 < 6; ++k6) {
                const int rb = k6 * 16 + quad * 4;
                U bu; bu.u4 = bfr[k6];
#pragma unroll
                for (int mt = 0; mt < 2; ++mt) {
                    const int px = mt * 16 + lo16;
                    U au;
                    au.i4.x = (int)lds[(rb + 0) * 33 + px];
                    au.i4.y = (int)lds[(rb + 1) * 33 + px];
                    au.i4.z = (int)lds[(rb + 2) * 33 + px];
                    au.i4.w = (int)lds[(rb + 3) * 33 + px];
                    acc[mt] = __builtin_amdgcn_mfma_f32_16x16x32_bf16(au.s8, bu.s8, acc[mt], 0, 0, 0);
                }
            }
        }
        float* op = outp + (size_t)(b * 64 + wvu * 16 + lo16) * HW + q0;
#pragma unroll
        for (int mt = 0; mt < 2; ++mt)
#pragma unroll
            for (int rg = 0; rg < 4; ++rg)
                op[mt * 16 + quad * 4 + rg] = acc[mt][rg];
    } else {
        // ---- mean of dy/dx channels
        int i = t - 1344;
        int lvl, j;
        if (i < 128) { lvl = 0; j = i; }
        else if (i < 160) { lvl = 1; j = i - 128; }
        else { lvl = 2; j = i - 160; }
        const int HW = 16384 >> (2 * lvl);
        const int nper = 64 >> (2 * lvl);
        const int qb = j % nper, b = j / nper;
        const float* OFFM = ws + (lvl == 0 ? 0 : (lvl == 1 ? 2359296 : 2949120));
        float* MEAN = ws + (lvl == 0 ? 4644864 : (lvl == 1 ? 4710400 : 4726784));
        const int q = qb * 256 + tid;
        const float* pp = OFFM + (size_t)b * 72 * HW + q;
        float sy = 0.f, sx = 0.f;
#pragma unroll
        for (int u = 0; u < 36; ++u) {
            sy += pp[(size_t)(2 * u) * HW];
            sx += pp[(size_t)(2 * u + 1) * HW];
        }
        MEAN[(size_t)(b * 2) * HW + q] = sy * (1.f / 36.f);
        MEAN[(size_t)(b * 2 + 1) * HW + q] = sx * (1.f / 36.f);
    }
}

// ---------------- K3: upsample only (3072) --------------------------------------------
__global__ __launch_bounds__(256) void k3_up(P p) {
    float* ws = p.ws;
    int flat = ((int)blockIdx.x * 256 + (int)threadIdx.x) * 4;
    int lvl = flat >> 20;
    int r = flat & 1048575;
    int b = r >> 19, c = (r >> 18) & 1;
    int pix = r & 262143;
    int yo = pix >> 9, xo = pix & 511;
    const int H = 128 >> lvl, W = H;
    const float* MEAN = ws + (lvl == 0 ? 4644864 : (lvl == 1 ? 4710400 : 4726784));
    const float* m = MEAN + (size_t)(b * 2 + c) * H * W;
    float* o = p.out + (lvl == 0 ? 4849664 : (lvl == 1 ? 3801088 : 2752512)) +
               ((size_t)(b * 2 + c) * 512 + yo) * 512 + xo;
    const float fs = (float)(4 << lvl);
    const float sc = (float)(H - 1) * (1.f / 511.f);
    float sy = yo * sc;
    int y0 = min((int)sy, H - 2);
    float wy = sy - (float)y0;
    float rr[4];
#pragma unroll
    for (int u = 0; u < 4; ++u) {
        float sx = (float)(xo + u) * sc;
        int x0 = min((int)sx, W - 2);
        float wx = sx - (float)x0;
        float v00 = m[y0 * W + x0], v01 = m[y0 * W + x0 + 1];
        float v10 = m[(y0 + 1) * W + x0], v11 = m[(y0 + 1) * W + x0 + 1];
        float r0 = v00 * (1.f - wy) + v10 * wy;
        float r1 = v01 * (1.f - wy) + v11 * wy;
        rr[u] = (r0 * (1.f - wx) + r1 * wx) * fs;
    }
    *(float4*)o = make_float4(rr[0], rr[1], rr[2], rr[3]);
}

extern "C" void kernel_launch(void* const* d_in, const int* in_sizes, int n_in,
                              void* d_out, int out_size, void* d_ws, size_t ws_size,
                              hipStream_t stream) {
    const float* fin[21];
    for (int i = 0; i < 21; ++i) fin[i] = (const float*)d_in[i];
    P p;
    if (in_sizes[1] == in_sizes[0]) {  // dict order sou1,ref1,sou2,ref2,sou3,ref3
        p.sou0 = fin[0]; p.ref0 = fin[1];
        p.sou1 = fin[2]; p.ref1 = fin[3];
        p.sou2 = fin[4]; p.ref2 = fin[5];
    } else {  // arg order
        p.sou0 = fin[0]; p.sou1 = fin[1]; p.sou2 = fin[2];
        p.ref0 = fin[3]; p.ref1 = fin[4]; p.ref2 = fin[5];
    }
    p.ob0 = fin[7]; p.mb0 = fin[9];
    p.ob1 = fin[12]; p.mb1 = fin[14];
    p.ob2 = fin[17]; p.mb2 = fin[19];
    p.out = (float*)d_out;
    p.ws = (float*)d_ws;

    repack_all<<<dim3(144, 3), 256, 0, stream>>>(
        fin[6], fin[8], fin[10], fin[11], fin[13], fin[15], fin[16], fin[18], fin[20],
        p.ws + 4730880);
    k1_prep<<<dim3(4032), 256, 0, stream>>>(p);
    k2_fused<<<dim3(1512), 256, 0, stream>>>(p);
    k3_up<<<dim3(3072), 256, 0, stream>>>(p);
}

// Round 15
// 184.977 us; speedup vs baseline: 1.9365x; 1.0070x over previous
//
#include <hip/hip_runtime.h>

typedef __attribute__((ext_vector_type(8))) short short8;
typedef __attribute__((ext_vector_type(4))) float f32x4;

__device__ __forceinline__ float sigmoidf_(float x) { return 1.f / (1.f + __expf(-x)); }
__device__ __forceinline__ unsigned bf16rne(float x) {
    unsigned b = __float_as_uint(x);
    return (b + 0x7FFFu + ((b >> 16) & 1u)) >> 16;
}

// ws layout (float words):
//   OFFM:  lvl0 @0 (2359296), lvl1 @2359296 (589824), lvl2 @2949120 (147456)
//   MOD:   lvl0 @3096576 (1179648), lvl1 @4276224 (294912), lvl2 @4571136 (73728)
//   MEAN:  lvl0 @4644864 (65536), lvl1 @4710400 (16384), lvl2 @4726784 (4096)
//   WREP:  @4730880, 3*62784 floats; per lvl as u32:
//          [0..18432) WB dgemm B-frags | [36864..41472) WBO | [41472..55296) WBM
//   XTb:   @4919232 as u32 (bf16 pairs, 8 u32/px): lvl0 +0 (1048576),
//          lvl1 +1048576 (262144), lvl2 +1310720 (65536)
// XTb is emitted by the mod-conv blocks from their staged LDS tile (the central
// 64 px of the [px][64ch] bf16 tile ARE the XTb records) — no separate transpose.

struct P {
    const float *sou0, *sou1, *sou2;
    const float *ref0, *ref1, *ref2;
    const float *ob0, *ob1, *ob2;
    const float *mb0, *mb1, *mb2;
    float* out;
    float* ws;
};

union U {
    uint4 u4; int4 i4; short8 s8; f32x4 f4;
};

// ---------------- K0: fused weight repack (all levels) --------------------------------
__global__ __launch_bounds__(256) void repack_all(
    const float* __restrict__ ow0, const float* __restrict__ mw0, const float* __restrict__ rw0,
    const float* __restrict__ ow1, const float* __restrict__ mw1, const float* __restrict__ rw1,
    const float* __restrict__ ow2, const float* __restrict__ mw2, const float* __restrict__ rw2,
    float* __restrict__ dst) {
    const int lvl = blockIdx.y;
    const float* ow = lvl == 0 ? ow0 : (lvl == 1 ? ow1 : ow2);
    const float* mw = lvl == 0 ? mw0 : (lvl == 1 ? mw1 : mw2);
    const float* rw = lvl == 0 ? rw0 : (lvl == 1 ? rw1 : rw2);
    unsigned* d = (unsigned*)(dst + lvl * 62784);
    int i = blockIdx.x * 256 + threadIdx.x;
    if (i < 18432) {  // WB (dgemm): ((wvu*18+ks)*64+lane)*4+jw
        int jw = i & 3;
        int lane = (i >> 2) & 63;
        int t3 = i >> 8;
        int ks = t3 % 18, wvu = t3 / 18;
        int o = wvu * 16 + (lane & 15);
        int c0 = ks * 32 + (lane >> 4) * 8 + 2 * jw;
        int g0 = c0 / 144, r0 = c0 % 144;
        int c1 = c0 + 1;
        int g1 = c1 / 144, r1 = c1 % 144;
        float w0 = rw[o * 576 + (g0 * 16 + (r0 & 15)) * 9 + (r0 >> 4)];
        float w1 = rw[o * 576 + (g1 * 16 + (r1 & 15)) * 9 + (r1 >> 4)];
        d[i] = bf16rne(w0) | (bf16rne(w1) << 16);
    } else if (i < 23040) {  // WBO
        int o2 = i - 18432;
        int jw = o2 & 3;
        int lane = (o2 >> 2) & 63;
        int t2 = o2 >> 8;
        int tap = t2 >> 1, nt = t2 & 1;
        int n = nt * 16 + (lane & 15);
        int ic0 = (lane >> 4) * 8 + 2 * jw;
        float w0 = (n < 18) ? ow[n * 288 + ic0 * 9 + tap] : 0.f;
        float w1 = (n < 18) ? ow[n * 288 + (ic0 + 1) * 9 + tap] : 0.f;
        d[36864 + o2] = bf16rne(w0) | (bf16rne(w1) << 16);
    } else if (i < 36864) {  // WBM
        int o3 = i - 23040;
        int jw = o3 & 3;
        int lane = (o3 >> 2) & 63;
        int t3 = o3 >> 8;
        int nt = t3 % 3, tc = t3 / 3;
        int tap = tc >> 1, c = tc & 1;
        int n = nt * 16 + (lane & 15);
        int ic0 = c * 32 + (lane >> 4) * 8 + 2 * jw;
        float w0 = (n < 36) ? mw[n * 576 + ic0 * 9 + tap] : 0.f;
        float w1 = (n < 36) ? mw[n * 576 + (ic0 + 1) * 9 + tap] : 0.f;
        d[41472 + o3] = bf16rne(w0) | (bf16rne(w1) << 16);
    }
}

// ---------------- K1: MFMA offset_conv(2688) + MFMA mod_conv+XTb(672) -----------------
// Staging writes are b128 (8 ch per uint4): stride-20/36 rows spread 8 consecutive
// lanes over all 32 banks (R13's per-dword staging was 8-way conflicted, 1.81M).
// Mod-conv blocks also emit XTb from their staged tile — the old transpose task's
// 19 MB sou re-read is gone.
__global__ __launch_bounds__(256) void k1_prep(P p) {
    __shared__ __align__(16) char smem[28512];
    const int t = blockIdx.x;
    float* ws = p.ws;
    const int tid = threadIdx.x;

    if (t < 2688) {  // ---- offset conv GEMM: 32ch -> 18(pad32), K=288
        int lvl, j;
        if (t < 2048) { lvl = 0; j = t; }
        else if (t < 2560) { lvl = 1; j = t - 2048; }
        else { lvl = 2; j = t - 2560; }
        const int logW = 7 - lvl;
        const int W = 1 << logW, H = W, HW = H * W;
        const int nper = 256 >> (2 * lvl);
        const int qb = j % nper, g = (j / nper) & 3, b = j / (nper * 4);
        const int q0 = qb * 64;
        const int hlo = q0 >> logW;
        const int xlo = q0 & (W - 1);
        const int cols = (W >= 64) ? 66 : 34;
        const int rcTot = (W >= 64) ? 198 : 136;
        const float* sou = lvl == 0 ? p.sou0 : (lvl == 1 ? p.sou1 : p.sou2);
        const float* ref = lvl == 0 ? p.ref0 : (lvl == 1 ? p.ref1 : p.ref2);
        const float* bases = sou + (size_t)(b * 64 + g * 16) * HW;
        const float* baser = ref + (size_t)(b * 64 + g * 16) * HW;
        unsigned* ldsW = (unsigned*)smem;  // row stride 20 dw (40 shorts)
        const bool sact = tid < rcTot;
        const int srow = tid / cols, scol = tid - srow * cols;
        const int grow = hlo - 1 + srow, gcol = xlo - 1 + scol;
        const bool inb = sact && grow >= 0 && grow < H && gcol >= 0 && gcol < W;
        const size_t goff = inb ? ((size_t)grow * W + gcol) : 0;
#pragma unroll
        for (int c8 = 0; c8 < 4; ++c8) {
            const float* p0 = (c8 < 2) ? bases + (size_t)(c8 * 8) * HW
                                       : baser + (size_t)((c8 - 2) * 8) * HW;
            float v[8];
#pragma unroll
            for (int jj = 0; jj < 8; ++jj) v[jj] = inb ? p0[(size_t)jj * HW + goff] : 0.f;
            if (sact) {
                uint4 wv;
                wv.x = bf16rne(v[0]) | (bf16rne(v[1]) << 16);
                wv.y = bf16rne(v[2]) | (bf16rne(v[3]) << 16);
                wv.z = bf16rne(v[4]) | (bf16rne(v[5]) << 16);
                wv.w = bf16rne(v[6]) | (bf16rne(v[7]) << 16);
                *(uint4*)&ldsW[tid * 20 + c8 * 4] = wv;
            }
        }
        __syncthreads();
        const int wvu = __builtin_amdgcn_readfirstlane(tid >> 6);
        const int lane = tid & 63, quad = lane >> 4, lo16 = lane & 15;
        const int qg = q0 + wvu * 16 + lo16;
        const int rowB = (qg >> logW) - hlo;
        const int colB = (qg & (W - 1)) - xlo;
        const unsigned short* ldsS = (const unsigned short*)smem;
        const unsigned* WBO = (const unsigned*)(ws + 4730880 + lvl * 62784) + 36864;
        f32x4 acc[2];
        acc[0] = (f32x4){0.f, 0.f, 0.f, 0.f};
        acc[1] = (f32x4){0.f, 0.f, 0.f, 0.f};
#pragma unroll
        for (int tap = 0; tap < 9; ++tap) {
            const int ky = tap / 3, kx = tap - ky * 3;
            const int rc = (rowB + ky) * cols + colB + kx;
            U au; au.s8 = *(const short8*)&ldsS[rc * 40 + quad * 8];
#pragma unroll
            for (int nt = 0; nt < 2; ++nt) {
                U bu; bu.u4 = *(const uint4*)(WBO + ((tap * 2 + nt) * 64 + lane) * 4);
                acc[nt] = __builtin_amdgcn_mfma_f32_16x16x32_bf16(au.s8, bu.s8, acc[nt], 0, 0, 0);
            }
        }
        const float* bias = lvl == 0 ? p.ob0 : (lvl == 1 ? p.ob1 : p.ob2);
        float* OFFM = ws + (lvl == 0 ? 0 : (lvl == 1 ? 2359296 : 2949120));
        const float rng = 0.25f * (float)H;
#pragma unroll
        for (int nt = 0; nt < 2; ++nt) {
            const int o = nt * 16 + lo16;
            if (o < 18) {
                const float bb = bias[o];
                float* op = OFFM + (size_t)(b * 72 + g * 18 + o) * HW + q0 + wvu * 16 + quad * 4;
#pragma unroll
                for (int rg = 0; rg < 4; ++rg)
                    op[rg] = rng * (2.f * sigmoidf_(acc[nt][rg] + bb) - 1.f);
            }
        }
    } else {  // ---- mod conv GEMM: 64ch -> 36(pad48), K=576 + XTb emission
        const int i1 = t - 2688;
        int lvl, j;
        if (i1 < 512) { lvl = 0; j = i1; }
        else if (i1 < 640) { lvl = 1; j = i1 - 512; }
        else { lvl = 2; j = i1 - 640; }
        const int logW = 7 - lvl;
        const int W = 1 << logW, H = W, HW = H * W;
        const int nper = 256 >> (2 * lvl);
        const int qb = j % nper, b = j / nper;
        const int q0 = qb * 64;
        const int hlo = q0 >> logW;
        const int xlo = q0 & (W - 1);
        const int cols = (W >= 64) ? 66 : 34;
        const int rcTot = (W >= 64) ? 198 : 136;
        const float* sou = lvl == 0 ? p.sou0 : (lvl == 1 ? p.sou1 : p.sou2);
        const float* base = sou + (size_t)b * 64 * HW;
        unsigned* ldsW = (unsigned*)smem;  // row stride 36 dw (72 shorts)
        const bool sact = tid < rcTot;
        const int srow = tid / cols, scol = tid - srow * cols;
        const int grow = hlo - 1 + srow, gcol = xlo - 1 + scol;
        const bool inb = sact && grow >= 0 && grow < H && gcol >= 0 && gcol < W;
        const size_t goff = inb ? ((size_t)grow * W + gcol) : 0;
#pragma unroll
        for (int c8 = 0; c8 < 8; ++c8) {
            const float* p0 = base + (size_t)(c8 * 8) * HW;
            float v[8];
#pragma unroll
            for (int jj = 0; jj < 8; ++jj) v[jj] = inb ? p0[(size_t)jj * HW + goff] : 0.f;
            if (sact) {
                uint4 wv;
                wv.x = bf16rne(v[0]) | (bf16rne(v[1]) << 16);
                wv.y = bf16rne(v[2]) | (bf16rne(v[3]) << 16);
                wv.z = bf16rne(v[4]) | (bf16rne(v[5]) << 16);
                wv.w = bf16rne(v[6]) | (bf16rne(v[7]) << 16);
                *(uint4*)&ldsW[tid * 36 + c8 * 4] = wv;
            }
        }
        __syncthreads();
        // ---- emit XTb for the central 64 px straight from the staged tile ----------
        unsigned* XTb = (unsigned*)(ws + 4919232) +
                        (lvl == 0 ? 0 : (lvl == 1 ? 1048576 : 1310720));
#pragma unroll
        for (int u = 0; u < 2; ++u) {
            const int idx = tid * 2 + u;       // 0..511
            const int px = idx >> 3, gh = idx & 7;
            const int g = gh >> 1, half = gh & 1;
            const int rc = ((px >> logW) + 1) * cols + (px & (W - 1)) + 1;
            uint4 v = *(const uint4*)&ldsW[rc * 36 + g * 8 + half * 4];
            *(uint4*)(XTb + ((size_t)(b * 4 + g) * HW + q0 + px) * 8 + half * 4) = v;
        }
        // ---- MFMA phase ------------------------------------------------------------
        const int wvu = __builtin_amdgcn_readfirstlane(tid >> 6);
        const int lane = tid & 63, quad = lane >> 4, lo16 = lane & 15;
        const int qg = q0 + wvu * 16 + lo16;
        const int rowB = (qg >> logW) - hlo;
        const int colB = (qg & (W - 1)) - xlo;
        const unsigned short* ldsS = (const unsigned short*)smem;
        const unsigned* WBM = (const unsigned*)(ws + 4730880 + lvl * 62784) + 41472;
        f32x4 acc[3];
        acc[0] = (f32x4){0.f, 0.f, 0.f, 0.f};
        acc[1] = (f32x4){0.f, 0.f, 0.f, 0.f};
        acc[2] = (f32x4){0.f, 0.f, 0.f, 0.f};
#pragma unroll
        for (int tap = 0; tap < 9; ++tap) {
            const int ky = tap / 3, kx = tap - ky * 3;
            const int rc = (rowB + ky) * cols + colB + kx;
#pragma unroll
            for (int c = 0; c < 2; ++c) {
                U au; au.s8 = *(const short8*)&ldsS[rc * 72 + c * 32 + quad * 8];
#pragma unroll
                for (int nt = 0; nt < 3; ++nt) {
                    U bu;
                    bu.u4 = *(const uint4*)(WBM + (((tap * 2 + c) * 3 + nt) * 64 + lane) * 4);
                    acc[nt] = __builtin_amdgcn_mfma_f32_16x16x32_bf16(au.s8, bu.s8, acc[nt], 0, 0, 0);
                }
            }
        }
        const float* bias = lvl == 0 ? p.mb0 : (lvl == 1 ? p.mb1 : p.mb2);
        float* MOD = ws + (lvl == 0 ? 3096576 : (lvl == 1 ? 4276224 : 4571136));
#pragma unroll
        for (int nt = 0; nt < 3; ++nt) {
            const int o = nt * 16 + lo16;
            if (o < 36) {
                const float bb = bias[o];
                float* op = MOD + (size_t)(b * 36 + o) * HW + q0 + wvu * 16 + quad * 4;
#pragma unroll
                for (int rg = 0; rg < 4; ++rg)
                    op[rg] = 2.f * sigmoidf_(acc[nt][rg] + bb);
            }
        }
    }
}

// ---------------- K2: FUSED gather+dgemm(1344, 32-px tiles) + mean(168) ---------------
__global__ __launch_bounds__(256) void k2_fused(P p) {
    __shared__ unsigned lds[96 * 33];  // 12.7 KB
    const int t = blockIdx.x;
    float* ws = p.ws;
    const int tid = threadIdx.x;
    if (t < 1344) {
        int lvl, j;
        if (t < 1024) { lvl = 0; j = t; }
        else if (t < 1280) { lvl = 1; j = t - 1024; }
        else { lvl = 2; j = t - 1280; }
        const int logW = 7 - lvl;
        const int W = 1 << logW, H = W, HW = H * W;
        const int nper = 512 >> (2 * lvl);
        const int qb = j % nper, b = j / nper;
        const int q0 = qb * 32;
        const float* OFFM = ws + (lvl == 0 ? 0 : (lvl == 1 ? 2359296 : 2949120));
        const float* MOD = ws + (lvl == 0 ? 3096576 : (lvl == 1 ? 4276224 : 4571136));
        const unsigned* XTb = (const unsigned*)(ws + 4919232) +
                              (lvl == 0 ? 0 : (lvl == 1 ? 1048576 : 1310720));
        const unsigned* WB = (const unsigned*)(ws + 4730880 + lvl * 62784);
        float* outp = p.out + (lvl == 0 ? 655360 : (lvl == 1 ? 131072 : 0));
        const int wvu = __builtin_amdgcn_readfirstlane(tid >> 6);
        const int lane = tid & 63, quad = lane >> 4, lo16 = lane & 15;
        f32x4 acc[2];
        acc[0] = (f32x4){0.f, 0.f, 0.f, 0.f};
        acc[1] = (f32x4){0.f, 0.f, 0.f, 0.f};
        for (int c = 0; c < 3; ++c) {
            if (c) __syncthreads();
            // ---- phase A: gather 12 gk x 32 px into LDS (384 tasks)
#pragma unroll
            for (int it = 0; it < 2; ++it) {
                const int task = it * 256 + tid;
                if (task < 384) {
                    const int gkl = task >> 5, px = task & 31;
                    const int gk = c * 12 + gkl;
                    const int g = gk / 9, k = gk - g * 9;
                    const int q = q0 + px;
                    const int h = q >> logW, xp = q & (W - 1);
                    const int ky = k / 3, kx = k - ky * 3;
                    float dy = OFFM[(size_t)(b * 72 + g * 18 + 2 * k) * HW + q];
                    float dx = OFFM[(size_t)(b * 72 + g * 18 + 2 * k + 1) * HW + q];
                    float m = MOD[(size_t)(b * 36 + g * 9 + k) * HW + q];
                    float py = (float)(h - 1 + ky) + dy;
                    float pxx = (float)(xp - 1 + kx) + dx;
                    float y0f = floorf(py), x0f = floorf(pxx);
                    float wy = py - y0f, wx = pxx - x0f;
                    int y0 = (int)y0f, x0 = (int)x0f;
                    const unsigned* xg = XTb + (size_t)(b * 4 + g) * HW * 8;
                    float s[16];
#pragma unroll
                    for (int cc = 0; cc < 16; ++cc) s[cc] = 0.f;
#pragma unroll
                    for (int cor = 0; cor < 4; ++cor) {
                        int yy = y0 + (cor >> 1), xx = x0 + (cor & 1);
                        float cw = ((cor >> 1) ? wy : 1.f - wy) * ((cor & 1) ? wx : 1.f - wx);
                        cw = (yy >= 0 && yy < H && xx >= 0 && xx < W) ? cw * m : 0.f;
                        int yc = min(max(yy, 0), H - 1), xc = min(max(xx, 0), W - 1);
                        const uint4* cp = (const uint4*)(xg + (size_t)((yc << logW) + xc) * 8);
                        unsigned cbuf[8];
                        *(uint4*)&cbuf[0] = cp[0];
                        *(uint4*)&cbuf[4] = cp[1];
#pragma unroll
                        for (int pr = 0; pr < 8; ++pr) {
                            float lo = __uint_as_float(cbuf[pr] << 16);
                            float hi = __uint_as_float(cbuf[pr] & 0xFFFF0000u);
                            s[2 * pr] = fmaf(cw, lo, s[2 * pr]);
                            s[2 * pr + 1] = fmaf(cw, hi, s[2 * pr + 1]);
                        }
                    }
#pragma unroll
                    for (int pr = 0; pr < 8; ++pr)
                        lds[(gkl * 8 + pr) * 33 + px] =
                            bf16rne(s[2 * pr]) | (bf16rne(s[2 * pr + 1]) << 16);
                }
            }
            __syncthreads();
            // ---- phase B: 6 MFMA k-steps, 2 m-tiles
            uint4 bfr[6];
#pragma unroll
            for (int k6 = 0; k6 < 6; ++k6)
                bfr[k6] = *(const uint4*)(WB + (((wvu * 18 + c * 6 + k6) * 64 + lane) << 2));
#pragma unroll
            for (int k6 = 0; k6 < 6; ++k6) {
                const int rb = k6 * 16 + quad * 4;
                U bu; bu.u4 = bfr[k6];
#pragma unroll
                for (int mt = 0; mt < 2; ++mt) {
                    const int px = mt * 16 + lo16;
                    U au;
                    au.i4.x = (int)lds[(rb + 0) * 33 + px];
                    au.i4.y = (int)lds[(rb + 1) * 33 + px];
                    au.i4.z = (int)lds[(rb + 2) * 33 + px];
                    au.i4.w = (int)lds[(rb + 3) * 33 + px];
                    acc[mt] = __builtin_amdgcn_mfma_f32_16x16x32_bf16(au.s8, bu.s8, acc[mt], 0, 0, 0);
                }
            }
        }
        float* op = outp + (size_t)(b * 64 + wvu * 16 + lo16) * HW + q0;
#pragma unroll
        for (int mt = 0; mt < 2; ++mt)
#pragma unroll
            for (int rg = 0; rg < 4; ++rg)
                op[mt * 16 + quad * 4 + rg] = acc[mt][rg];
    } else {
        // ---- mean of dy/dx channels
        int i = t - 1344;
        int lvl, j;
        if (i < 128) { lvl = 0; j = i; }
        else if (i < 160) { lvl = 1; j = i - 128; }
        else { lvl = 2; j = i - 160; }
        const int HW = 16384 >> (2 * lvl);
        const int nper = 64 >> (2 * lvl);
        const int qb = j % nper, b = j / nper;
        const float* OFFM = ws + (lvl == 0 ? 0 : (lvl == 1 ? 2359296 : 2949120));
        float* MEAN = ws + (lvl == 0 ? 4644864 : (lvl == 1 ? 4710400 : 4726784));
        const int q = qb * 256 + tid;
        const float* pp = OFFM + (size_t)b * 72 * HW + q;
        float sy = 0.f, sx = 0.f;
#pragma unroll
        for (int u = 0; u < 36; ++u) {
            sy += pp[(size_t)(2 * u) * HW];
            sx += pp[(size_t)(2 * u + 1) * HW];
        }
        MEAN[(size_t)(b * 2) * HW + q] = sy * (1.f / 36.f);
        MEAN[(size_t)(b * 2 + 1) * HW + q] = sx * (1.f / 36.f);
    }
}

// ---------------- K3: upsample only (3072) --------------------------------------------
__global__ __launch_bounds__(256) void k3_up(P p) {
    float* ws = p.ws;
    int flat = ((int)blockIdx.x * 256 + (int)threadIdx.x) * 4;
    int lvl = flat >> 20;
    int r = flat & 1048575;
    int b = r >> 19, c = (r >> 18) & 1;
    int pix = r & 262143;
    int yo = pix >> 9, xo = pix & 511;
    const int H = 128 >> lvl, W = H;
    const float* MEAN = ws + (lvl == 0 ? 4644864 : (lvl == 1 ? 4710400 : 4726784));
    const float* m = MEAN + (size_t)(b * 2 + c) * H * W;
    float* o = p.out + (lvl == 0 ? 4849664 : (lvl == 1 ? 3801088 : 2752512)) +
               ((size_t)(b * 2 + c) * 512 + yo) * 512 + xo;
    const float fs = (float)(4 << lvl);
    const float sc = (float)(H - 1) * (1.f / 511.f);
    float sy = yo * sc;
    int y0 = min((int)sy, H - 2);
    float wy = sy - (float)y0;
    float rr[4];
#pragma unroll
    for (int u = 0; u < 4; ++u) {
        float sx = (float)(xo + u) * sc;
        int x0 = min((int)sx, W - 2);
        float wx = sx - (float)x0;
        float v00 = m[y0 * W + x0], v01 = m[y0 * W + x0 + 1];
        float v10 = m[(y0 + 1) * W + x0], v11 = m[(y0 + 1) * W + x0 + 1];
        float r0 = v00 * (1.f - wy) + v10 * wy;
        float r1 = v01 * (1.f - wy) + v11 * wy;
        rr[u] = (r0 * (1.f - wx) + r1 * wx) * fs;
    }
    *(float4*)o = make_float4(rr[0], rr[1], rr[2], rr[3]);
}

extern "C" void kernel_launch(void* const* d_in, const int* in_sizes, int n_in,
                              void* d_out, int out_size, void* d_ws, size_t ws_size,
                              hipStream_t stream) {
    const float* fin[21];
    for (int i = 0; i < 21; ++i) fin[i] = (const float*)d_in[i];
    P p;
    if (in_sizes[1] == in_sizes[0]) {  // dict order sou1,ref1,sou2,ref2,sou3,ref3
        p.sou0 = fin[0]; p.ref0 = fin[1];
        p.sou1 = fin[2]; p.ref1 = fin[3];
        p.sou2 = fin[4]; p.ref2 = fin[5];
    } else {  // arg order
        p.sou0 = fin[0]; p.sou1 = fin[1]; p.sou2 = fin[2];
        p.ref0 = fin[3]; p.ref1 = fin[4]; p.ref2 = fin[5];
    }
    p.ob0 = fin[7]; p.mb0 = fin[9];
    p.ob1 = fin[12]; p.mb1 = fin[14];
    p.ob2 = fin[17]; p.mb2 = fin[19];
    p.out = (float*)d_out;
    p.ws = (float*)d_ws;

    repack_all<<<dim3(144, 3), 256, 0, stream>>>(
        fin[6], fin[8], fin[10], fin[11], fin[13], fin[15], fin[16], fin[18], fin[20],
        p.ws + 4730880);
    k1_prep<<<dim3(3360), 256, 0, stream>>>(p);
    k2_fused<<<dim3(1512), 256, 0, stream>>>(p);
    k3_up<<<dim3(3072), 256, 0, stream>>>(p);
}

// Round 16
// 180.291 us; speedup vs baseline: 1.9868x; 1.0260x over previous
//
#include <hip/hip_runtime.h>

typedef __attribute__((ext_vector_type(8))) short short8;
typedef __attribute__((ext_vector_type(4))) float f32x4;

__device__ __forceinline__ float sigmoidf_(float x) { return 1.f / (1.f + __expf(-x)); }
__device__ __forceinline__ unsigned bf16rne(float x) {
    unsigned b = __float_as_uint(x);
    return (b + 0x7FFFu + ((b >> 16) & 1u)) >> 16;
}

// ws layout (float words):
//   OFFM:  lvl0 @0 (2359296), lvl1 @2359296 (589824), lvl2 @2949120 (147456)
//   MOD:   lvl0 @3096576 (1179648), lvl1 @4276224 (294912), lvl2 @4571136 (73728)
//   MEAN:  lvl0 @4644864 (65536), lvl1 @4710400 (16384), lvl2 @4726784 (4096)
//   WREP:  @4730880, 3*62784 floats; per lvl as u32:
//          [0..18432)     WB   dgemm B-frags
//          [36864..41984) WBO2 offset-conv B-frags, split-half K:
//                         ((h*5+ks)*2+nt)*64*4 ; K = tap*16+ch, pad tap 9 = 0
//          [41984..55808) WBM  mod-conv B-frags (taps9 x chunk2 x nt3)
//   XTb:   @4919232 as u32 (bf16 pairs, 8 u32/px): lvl0 +0 (1048576),
//          lvl1 +1048576 (262144), lvl2 +1310720 (65536)
// k1 blocks (672) do: stage sou64 -> mod GEMM + offset half0 (all 4 groups, shared
// weights) + XTb emit -> re-stage ref64 in place -> offset half1. Offset conv no
// longer has its own blocks (R15: they duplicated 64ch of staging per tile).

struct P {
    const float *sou0, *sou1, *sou2;
    const float *ref0, *ref1, *ref2;
    const float *ob0, *ob1, *ob2;
    const float *mb0, *mb1, *mb2;
    float* out;
    float* ws;
};

union U {
    uint4 u4; int4 i4; short8 s8; f32x4 f4;
};

// ---------------- K0: fused weight repack (all levels) --------------------------------
__global__ __launch_bounds__(256) void repack_all(
    const float* __restrict__ ow0, const float* __restrict__ mw0, const float* __restrict__ rw0,
    const float* __restrict__ ow1, const float* __restrict__ mw1, const float* __restrict__ rw1,
    const float* __restrict__ ow2, const float* __restrict__ mw2, const float* __restrict__ rw2,
    float* __restrict__ dst) {
    const int lvl = blockIdx.y;
    const float* ow = lvl == 0 ? ow0 : (lvl == 1 ? ow1 : ow2);
    const float* mw = lvl == 0 ? mw0 : (lvl == 1 ? mw1 : mw2);
    const float* rw = lvl == 0 ? rw0 : (lvl == 1 ? rw1 : rw2);
    unsigned* d = (unsigned*)(dst + lvl * 62784);
    int i = blockIdx.x * 256 + threadIdx.x;
    if (i < 18432) {  // WB (dgemm): ((wvu*18+ks)*64+lane)*4+jw
        int jw = i & 3;
        int lane = (i >> 2) & 63;
        int t3 = i >> 8;
        int ks = t3 % 18, wvu = t3 / 18;
        int o = wvu * 16 + (lane & 15);
        int c0 = ks * 32 + (lane >> 4) * 8 + 2 * jw;
        int g0 = c0 / 144, r0 = c0 % 144;
        int c1 = c0 + 1;
        int g1 = c1 / 144, r1 = c1 % 144;
        float w0 = rw[o * 576 + (g0 * 16 + (r0 & 15)) * 9 + (r0 >> 4)];
        float w1 = rw[o * 576 + (g1 * 16 + (r1 & 15)) * 9 + (r1 >> 4)];
        d[i] = bf16rne(w0) | (bf16rne(w1) << 16);
    } else if (i < 23552) {  // WBO2: split-half offset B-frags (5120 u32)
        int o2 = i - 18432;
        int jw = o2 & 3;
        int lane = (o2 >> 2) & 63;
        int t2 = o2 >> 8;          // 0..19 = (h*5+ks)*2+nt
        int nt = t2 & 1;
        int hk = t2 >> 1;          // 0..9
        int ks = hk % 5, h = hk / 5;
        int n = nt * 16 + (lane & 15);
        int K = ks * 32 + (lane >> 4) * 8 + 2 * jw;
        int tap = K >> 4, ch = K & 15;
        bool ok = (n < 18) && (tap < 9);
        float w0 = ok ? ow[n * 288 + (h * 16 + ch) * 9 + tap] : 0.f;
        float w1 = ok ? ow[n * 288 + (h * 16 + ch + 1) * 9 + tap] : 0.f;
        d[36864 + o2] = bf16rne(w0) | (bf16rne(w1) << 16);
    } else if (i < 37376) {  // WBM (13824 u32) at 41984
        int o3 = i - 23552;
        int jw = o3 & 3;
        int lane = (o3 >> 2) & 63;
        int t3 = o3 >> 8;           // 0..53
        int nt = t3 % 3, tc = t3 / 3;
        int tap = tc >> 1, c = tc & 1;
        int n = nt * 16 + (lane & 15);
        int ic0 = c * 32 + (lane >> 4) * 8 + 2 * jw;
        float w0 = (n < 36) ? mw[n * 576 + ic0 * 9 + tap] : 0.f;
        float w1 = (n < 36) ? mw[n * 576 + (ic0 + 1) * 9 + tap] : 0.f;
        d[41984 + o3] = bf16rne(w0) | (bf16rne(w1) << 16);
    }
}

// ---------------- K1: fused mod+offset conv + XTb (672 blocks) ------------------------
__global__ __launch_bounds__(256) void k1_prep(P p) {
    __shared__ __align__(16) char smem[28512];  // 198 rows x 72 shorts
    const int t = blockIdx.x;
    float* ws = p.ws;
    const int tid = threadIdx.x;

    int lvl, j;
    if (t < 512) { lvl = 0; j = t; }
    else if (t < 640) { lvl = 1; j = t - 512; }
    else { lvl = 2; j = t - 640; }
    const int logW = 7 - lvl;
    const int W = 1 << logW, H = W, HW = H * W;
    const int nper = 256 >> (2 * lvl);
    const int qb = j % nper, b = j / nper;
    const int q0 = qb * 64;
    const int hlo = q0 >> logW;
    const int xlo = q0 & (W - 1);
    const int cols = (W >= 64) ? 66 : 34;
    const int rcTot = (W >= 64) ? 198 : 136;
    const float* sou = lvl == 0 ? p.sou0 : (lvl == 1 ? p.sou1 : p.sou2);
    const float* ref = lvl == 0 ? p.ref0 : (lvl == 1 ? p.ref1 : p.ref2);
    const float* base_s = sou + (size_t)b * 64 * HW;
    const float* base_r = ref + (size_t)b * 64 * HW;
    unsigned* ldsW = (unsigned*)smem;  // row stride 36 dw (72 shorts)
    const bool sact = tid < rcTot;
    const int srow = tid / cols, scol = tid - srow * cols;
    const int grow = hlo - 1 + srow, gcol = xlo - 1 + scol;
    const bool inb = sact && grow >= 0 && grow < H && gcol >= 0 && gcol < W;
    const size_t goff = inb ? ((size_t)grow * W + gcol) : 0;

    // ---- stage sou (64 ch, b128 writes: stride-36 rows spread lanes over banks) ------
#pragma unroll
    for (int c8 = 0; c8 < 8; ++c8) {
        const float* p0 = base_s + (size_t)(c8 * 8) * HW;
        float v[8];
#pragma unroll
        for (int jj = 0; jj < 8; ++jj) v[jj] = inb ? p0[(size_t)jj * HW + goff] : 0.f;
        if (sact) {
            uint4 wv;
            wv.x = bf16rne(v[0]) | (bf16rne(v[1]) << 16);
            wv.y = bf16rne(v[2]) | (bf16rne(v[3]) << 16);
            wv.z = bf16rne(v[4]) | (bf16rne(v[5]) << 16);
            wv.w = bf16rne(v[6]) | (bf16rne(v[7]) << 16);
            *(uint4*)&ldsW[tid * 36 + c8 * 4] = wv;
        }
    }
    __syncthreads();

    // ---- emit XTb for the central 64 px straight from the staged sou tile -----------
    unsigned* XTb = (unsigned*)(ws + 4919232) +
                    (lvl == 0 ? 0 : (lvl == 1 ? 1048576 : 1310720));
#pragma unroll
    for (int u = 0; u < 2; ++u) {
        const int idx = tid * 2 + u;       // 0..511
        const int px = idx >> 3, gh = idx & 7;
        const int g = gh >> 1, half = gh & 1;
        const int rc = ((px >> logW) + 1) * cols + (px & (W - 1)) + 1;
        uint4 v = *(const uint4*)&ldsW[rc * 36 + g * 8 + half * 4];
        *(uint4*)(XTb + ((size_t)(b * 4 + g) * HW + q0 + px) * 8 + half * 4) = v;
    }

    // ---- MFMA phase on sou tile: mod conv + offset half0 ----------------------------
    const int wvu = __builtin_amdgcn_readfirstlane(tid >> 6);
    const int lane = tid & 63, quad = lane >> 4, lo16 = lane & 15;
    const int qg = q0 + wvu * 16 + lo16;
    const int rowB = (qg >> logW) - hlo;
    const int colB = (qg & (W - 1)) - xlo;
    const unsigned short* ldsS = (const unsigned short*)smem;
    const unsigned* WREPu = (const unsigned*)(ws + 4730880 + lvl * 62784);
    const unsigned* WBO2 = WREPu + 36864;
    const unsigned* WBM = WREPu + 41984;

    f32x4 accM[3], accO[4][2];
#pragma unroll
    for (int nt = 0; nt < 3; ++nt) accM[nt] = (f32x4){0.f, 0.f, 0.f, 0.f};
#pragma unroll
    for (int g = 0; g < 4; ++g)
#pragma unroll
        for (int nt = 0; nt < 2; ++nt) accO[g][nt] = (f32x4){0.f, 0.f, 0.f, 0.f};

    // mod conv: 9 taps x 2 chunks x 3 ntiles
#pragma unroll
    for (int tap = 0; tap < 9; ++tap) {
        const int ky = tap / 3, kx = tap - ky * 3;
        const int rc = (rowB + ky) * cols + colB + kx;
#pragma unroll
        for (int c = 0; c < 2; ++c) {
            U au; au.s8 = *(const short8*)&ldsS[rc * 72 + c * 32 + quad * 8];
#pragma unroll
            for (int nt = 0; nt < 3; ++nt) {
                U bu;
                bu.u4 = *(const uint4*)(WBM + (((tap * 2 + c) * 3 + nt) * 64 + lane) * 4);
                accM[nt] = __builtin_amdgcn_mfma_f32_16x16x32_bf16(au.s8, bu.s8, accM[nt], 0, 0, 0);
            }
        }
    }
    // offset half0 (sou): K padded 160, tap = Kbase>>4 per quad
#pragma unroll
    for (int ks = 0; ks < 5; ++ks) {
        const int Kbase = ks * 32 + quad * 8;
        const int tap = min(Kbase >> 4, 8);
        const int ky = tap / 3, kx = tap - ky * 3;
        const int rc = (rowB + ky) * cols + colB + kx;
        const int choff = Kbase & 15;  // 0 or 8
#pragma unroll
        for (int g = 0; g < 4; ++g) {
            U au; au.s8 = *(const short8*)&ldsS[rc * 72 + g * 16 + choff];
#pragma unroll
            for (int nt = 0; nt < 2; ++nt) {
                U bu;
                bu.u4 = *(const uint4*)(WBO2 + ((ks * 2 + nt) * 64 + lane) * 4);
                accO[g][nt] =
                    __builtin_amdgcn_mfma_f32_16x16x32_bf16(au.s8, bu.s8, accO[g][nt], 0, 0, 0);
            }
        }
    }
    __syncthreads();

    // ---- re-stage ref (64 ch) in place ----------------------------------------------
#pragma unroll
    for (int c8 = 0; c8 < 8; ++c8) {
        const float* p0 = base_r + (size_t)(c8 * 8) * HW;
        float v[8];
#pragma unroll
        for (int jj = 0; jj < 8; ++jj) v[jj] = inb ? p0[(size_t)jj * HW + goff] : 0.f;
        if (sact) {
            uint4 wv;
            wv.x = bf16rne(v[0]) | (bf16rne(v[1]) << 16);
            wv.y = bf16rne(v[2]) | (bf16rne(v[3]) << 16);
            wv.z = bf16rne(v[4]) | (bf16rne(v[5]) << 16);
            wv.w = bf16rne(v[6]) | (bf16rne(v[7]) << 16);
            *(uint4*)&ldsW[tid * 36 + c8 * 4] = wv;
        }
    }
    __syncthreads();

    // ---- offset half1 (ref) ----------------------------------------------------------
#pragma unroll
    for (int ks = 0; ks < 5; ++ks) {
        const int Kbase = ks * 32 + quad * 8;
        const int tap = min(Kbase >> 4, 8);
        const int ky = tap / 3, kx = tap - ky * 3;
        const int rc = (rowB + ky) * cols + colB + kx;
        const int choff = Kbase & 15;
#pragma unroll
        for (int g = 0; g < 4; ++g) {
            U au; au.s8 = *(const short8*)&ldsS[rc * 72 + g * 16 + choff];
#pragma unroll
            for (int nt = 0; nt < 2; ++nt) {
                U bu;
                bu.u4 = *(const uint4*)(WBO2 + (((5 + ks) * 2 + nt) * 64 + lane) * 4);
                accO[g][nt] =
                    __builtin_amdgcn_mfma_f32_16x16x32_bf16(au.s8, bu.s8, accO[g][nt], 0, 0, 0);
            }
        }
    }

    // ---- epilogues ------------------------------------------------------------------
    {
        const float* bias = lvl == 0 ? p.mb0 : (lvl == 1 ? p.mb1 : p.mb2);
        float* MOD = ws + (lvl == 0 ? 3096576 : (lvl == 1 ? 4276224 : 4571136));
#pragma unroll
        for (int nt = 0; nt < 3; ++nt) {
            const int o = nt * 16 + lo16;
            if (o < 36) {
                const float bb = bias[o];
                float* op = MOD + (size_t)(b * 36 + o) * HW + q0 + wvu * 16 + quad * 4;
#pragma unroll
                for (int rg = 0; rg < 4; ++rg)
                    op[rg] = 2.f * sigmoidf_(accM[nt][rg] + bb);
            }
        }
    }
    {
        const float* bias = lvl == 0 ? p.ob0 : (lvl == 1 ? p.ob1 : p.ob2);
        float* OFFM = ws + (lvl == 0 ? 0 : (lvl == 1 ? 2359296 : 2949120));
        const float rng = 0.25f * (float)H;
#pragma unroll
        for (int g = 0; g < 4; ++g)
#pragma unroll
            for (int nt = 0; nt < 2; ++nt) {
                const int o = nt * 16 + lo16;
                if (o < 18) {
                    const float bb = bias[o];
                    float* op = OFFM + (size_t)(b * 72 + g * 18 + o) * HW + q0 + wvu * 16 + quad * 4;
#pragma unroll
                    for (int rg = 0; rg < 4; ++rg)
                        op[rg] = rng * (2.f * sigmoidf_(accO[g][nt][rg] + bb) - 1.f);
                }
            }
    }
}

// ---------------- K2: FUSED gather+dgemm(1344, 32-px tiles) + mean(168) ---------------
__global__ __launch_bounds__(256) void k2_fused(P p) {
    __shared__ unsigned lds[96 * 33];  // 12.7 KB
    const int t = blockIdx.x;
    float* ws = p.ws;
    const int tid = threadIdx.x;
    if (t < 1344) {
        int lvl, j;
        if (t < 1024) { lvl = 0; j = t; }
        else if (t < 1280) { lvl = 1; j = t - 1024; }
        else { lvl = 2; j = t - 1280; }
        const int logW = 7 - lvl;
        const int W = 1 << logW, H = W, HW = H * W;
        const int nper = 512 >> (2 * lvl);
        const int qb = j % nper, b = j / nper;
        const int q0 = qb * 32;
        const float* OFFM = ws + (lvl == 0 ? 0 : (lvl == 1 ? 2359296 : 2949120));
        const float* MOD = ws + (lvl == 0 ? 3096576 : (lvl == 1 ? 4276224 : 4571136));
        const unsigned* XTb = (const unsigned*)(ws + 4919232) +
                              (lvl == 0 ? 0 : (lvl == 1 ? 1048576 : 1310720));
        const unsigned* WB = (const unsigned*)(ws + 4730880 + lvl * 62784);
        float* outp = p.out + (lvl == 0 ? 655360 : (lvl == 1 ? 131072 : 0));
        const int wvu = __builtin_amdgcn_readfirstlane(tid >> 6);
        const int lane = tid & 63, quad = lane >> 4, lo16 = lane & 15;
        f32x4 acc[2];
        acc[0] = (f32x4){0.f, 0.f, 0.f, 0.f};
        acc[1] = (f32x4){0.f, 0.f, 0.f, 0.f};
        for (int c = 0; c < 3; ++c) {
            if (c) __syncthreads();
#pragma unroll
            for (int it = 0; it < 2; ++it) {
                const int task = it * 256 + tid;
                if (task < 384) {
                    const int gkl = task >> 5, px = task & 31;
                    const int gk = c * 12 + gkl;
                    const int g = gk / 9, k = gk - g * 9;
                    const int q = q0 + px;
                    const int h = q >> logW, xp = q & (W - 1);
                    const int ky = k / 3, kx = k - ky * 3;
                    float dy = OFFM[(size_t)(b * 72 + g * 18 + 2 * k) * HW + q];
                    float dx = OFFM[(size_t)(b * 72 + g * 18 + 2 * k + 1) * HW + q];
                    float m = MOD[(size_t)(b * 36 + g * 9 + k) * HW + q];
                    float py = (float)(h - 1 + ky) + dy;
                    float pxx = (float)(xp - 1 + kx) + dx;
                    float y0f = floorf(py), x0f = floorf(pxx);
                    float wy = py - y0f, wx = pxx - x0f;
                    int y0 = (int)y0f, x0 = (int)x0f;
                    const unsigned* xg = XTb + (size_t)(b * 4 + g) * HW * 8;
                    float s[16];
#pragma unroll
                    for (int cc = 0; cc < 16; ++cc) s[cc] = 0.f;
#pragma unroll
                    for (int cor = 0; cor < 4; ++cor) {
                        int yy = y0 + (cor >> 1), xx = x0 + (cor & 1);
                        float cw = ((cor >> 1) ? wy : 1.f - wy) * ((cor & 1) ? wx : 1.f - wx);
                        cw = (yy >= 0 && yy < H && xx >= 0 && xx < W) ? cw * m : 0.f;
                        int yc = min(max(yy, 0), H - 1), xc = min(max(xx, 0), W - 1);
                        const uint4* cp = (const uint4*)(xg + (size_t)((yc << logW) + xc) * 8);
                        unsigned cbuf[8];
                        *(uint4*)&cbuf[0] = cp[0];
                        *(uint4*)&cbuf[4] = cp[1];
#pragma unroll
                        for (int pr = 0; pr < 8; ++pr) {
                            float lo = __uint_as_float(cbuf[pr] << 16);
                            float hi = __uint_as_float(cbuf[pr] & 0xFFFF0000u);
                            s[2 * pr] = fmaf(cw, lo, s[2 * pr]);
                            s[2 * pr + 1] = fmaf(cw, hi, s[2 * pr + 1]);
                        }
                    }
#pragma unroll
                    for (int pr = 0; pr < 8; ++pr)
                        lds[(gkl * 8 + pr) * 33 + px] =
                            bf16rne(s[2 * pr]) | (bf16rne(s[2 * pr + 1]) << 16);
                }
            }
            __syncthreads();
            uint4 bfr[6];
#pragma unroll
            for (int k6 = 0; k6 < 6; ++k6)
                bfr[k6] = *(const uint4*)(WB + (((wvu * 18 + c * 6 + k6) * 64 + lane) << 2));
#pragma unroll
            for (int k6 = 0; k6 < 6; ++k6) {
                const int rb = k6 * 16 + quad * 4;
                U bu; bu.u4 = bfr[k6];
#pragma unroll
                for (int mt = 0; mt < 2; ++mt) {
                    const int px = mt * 16 + lo16;
                    U au;
                    au.i4.x = (int)lds[(rb + 0) * 33 + px];
                    au.i4.y = (int)lds[(rb + 1) * 33 + px];
                    au.i4.z = (int)lds[(rb + 2) * 33 + px];
                    au.i4.w = (int)lds[(rb + 3) * 33 + px];
                    acc[mt] = __builtin_amdgcn_mfma_f32_16x16x32_bf16(au.s8, bu.s8, acc[mt], 0, 0, 0);
                }
            }
        }
        float* op = outp + (size_t)(b * 64 + wvu * 16 + lo16) * HW + q0;
#pragma unroll
        for (int mt = 0; mt < 2; ++mt)
#pragma unroll
            for (int rg = 0; rg < 4; ++rg)
                op[mt * 16 + quad * 4 + rg] = acc[mt][rg];
    } else {
        int i = t - 1344;
        int lvl, j;
        if (i < 128) { lvl = 0; j = i; }
        else if (i < 160) { lvl = 1; j = i - 128; }
        else { lvl = 2; j = i - 160; }
        const int HW = 16384 >> (2 * lvl);
        const int nper = 64 >> (2 * lvl);
        const int qb = j % nper, b = j / nper;
        const float* OFFM = ws + (lvl == 0 ? 0 : (lvl == 1 ? 2359296 : 2949120));
        float* MEAN = ws + (lvl == 0 ? 4644864 : (lvl == 1 ? 4710400 : 4726784));
        const int q = qb * 256 + tid;
        const float* pp = OFFM + (size_t)b * 72 * HW + q;
        float sy = 0.f, sx = 0.f;
#pragma unroll
        for (int u = 0; u < 36; ++u) {
            sy += pp[(size_t)(2 * u) * HW];
            sx += pp[(size_t)(2 * u + 1) * HW];
        }
        MEAN[(size_t)(b * 2) * HW + q] = sy * (1.f / 36.f);
        MEAN[(size_t)(b * 2 + 1) * HW + q] = sx * (1.f / 36.f);
    }
}

// ---------------- K3: upsample only (3072) --------------------------------------------
__global__ __launch_bounds__(256) void k3_up(P p) {
    float* ws = p.ws;
    int flat = ((int)blockIdx.x * 256 + (int)threadIdx.x) * 4;
    int lvl = flat >> 20;
    int r = flat & 1048575;
    int b = r >> 19, c = (r >> 18) & 1;
    int pix = r & 262143;
    int yo = pix >> 9, xo = pix & 511;
    const int H = 128 >> lvl, W = H;
    const float* MEAN = ws + (lvl == 0 ? 4644864 : (lvl == 1 ? 4710400 : 4726784));
    const float* m = MEAN + (size_t)(b * 2 + c) * H * W;
    float* o = p.out + (lvl == 0 ? 4849664 : (lvl == 1 ? 3801088 : 2752512)) +
               ((size_t)(b * 2 + c) * 512 + yo) * 512 + xo;
    const float fs = (float)(4 << lvl);
    const float sc = (float)(H - 1) * (1.f / 511.f);
    float sy = yo * sc;
    int y0 = min((int)sy, H - 2);
    float wy = sy - (float)y0;
    float rr[4];
#pragma unroll
    for (int u = 0; u < 4; ++u) {
        float sx = (float)(xo + u) * sc;
        int x0 = min((int)sx, W - 2);
        float wx = sx - (float)x0;
        float v00 = m[y0 * W + x0], v01 = m[y0 * W + x0 + 1];
        float v10 = m[(y0 + 1) * W + x0], v11 = m[(y0 + 1) * W + x0 + 1];
        float r0 = v00 * (1.f - wy) + v10 * wy;
        float r1 = v01 * (1.f - wy) + v11 * wy;
        rr[u] = (r0 * (1.f - wx) + r1 * wx) * fs;
    }
    *(float4*)o = make_float4(rr[0], rr[1], rr[2], rr[3]);
}

extern "C" void kernel_launch(void* const* d_in, const int* in_sizes, int n_in,
                              void* d_out, int out_size, void* d_ws, size_t ws_size,
                              hipStream_t stream) {
    const float* fin[21];
    for (int i = 0; i < 21; ++i) fin[i] = (const float*)d_in[i];
    P p;
    if (in_sizes[1] == in_sizes[0]) {  // dict order sou1,ref1,sou2,ref2,sou3,ref3
        p.sou0 = fin[0]; p.ref0 = fin[1];
        p.sou1 = fin[2]; p.ref1 = fin[3];
        p.sou2 = fin[4]; p.ref2 = fin[5];
    } else {  // arg order
        p.sou0 = fin[0]; p.sou1 = fin[1]; p.sou2 = fin[2];
        p.ref0 = fin[3]; p.ref1 = fin[4]; p.ref2 = fin[5];
    }
    p.ob0 = fin[7]; p.mb0 = fin[9];
    p.ob1 = fin[12]; p.mb1 = fin[14];
    p.ob2 = fin[17]; p.mb2 = fin[19];
    p.out = (float*)d_out;
    p.ws = (float*)d_ws;

    repack_all<<<dim3(146, 3), 256, 0, stream>>>(
        fin[6], fin[8], fin[10], fin[11], fin[13], fin[15], fin[16], fin[18], fin[20],
        p.ws + 4730880);
    k1_prep<<<dim3(672), 256, 0, stream>>>(p);
    k2_fused<<<dim3(1512), 256, 0, stream>>>(p);
    k3_up<<<dim3(3072), 256, 0, stream>>>(p);
}